// Round 9
// baseline (1355.018 us; speedup 1.0000x reference)
//
#include <hip/hip_runtime.h>
#include <math.h>

namespace {
constexpr int kB = 2;
constexpr int kN = 1024;
constexpr int kM = 16384;
constexpr float kSqrt3 = 1.7320508075688772f;

// workspace layout (bytes)
constexpr size_t A_BYTES = (size_t)kB * kN * kN * 4;
constexpr size_t DG_BYTES = (size_t)kB * 8 * 128 * 128 * 4;
constexpr size_t Z_BYTES = (size_t)kB * kN * 4;
constexpr size_t LH_BYTES = (size_t)kB * kN * kN * 2;
constexpr size_t DH_BYTES = (size_t)kB * 8 * 128 * 128 * 2;
constexpr size_t A_OFF = 0;
constexpr size_t DG_OFF = A_OFF + A_BYTES;
constexpr size_t Z_OFF = DG_OFF + DG_BYTES;
constexpr size_t LH_OFF = Z_OFF + Z_BYTES;
constexpr size_t LL_OFF = LH_OFF + LH_BYTES;   // (unused)
constexpr size_t DH_OFF = LL_OFF + LH_BYTES;
constexpr size_t DL_OFF = DH_OFF + DH_BYTES;
constexpr size_t WS_BYTES = DL_OFF + DH_BYTES;

// dynamic-LDS float offsets for panel/syrk kernels
constexpr int PAN_AT = 0;            // 128*132
constexpr int PAN_DT = 16896;        // 128*132
constexpr int PAN_TT = 33792;        // 3*32*33 = 3168
constexpr int PAN_FLOATS = 36960;    // 147840 bytes
constexpr int SYR_L1 = 0;            // 128*129
constexpr int SYR_L2 = 16512;        // 128*129
}  // namespace

typedef __attribute__((ext_vector_type(8))) short short8v;
typedef __attribute__((ext_vector_type(4))) float floatx4;

__device__ __forceinline__ float b16f(unsigned short h) {
  return __uint_as_float(((unsigned)h) << 16);
}
__device__ __forceinline__ unsigned short b16rn(float x) {
  unsigned u = __float_as_uint(x);
  unsigned r = u + 0x7FFFu + ((u >> 16) & 1u);
  return (unsigned short)(r >> 16);
}
__device__ __forceinline__ void split_bf16(float x, unsigned short& h, unsigned short& l) {
  unsigned u = __float_as_uint(x);
  h = (unsigned short)(u >> 16);
  float rem = x - b16f(h);
  l = (unsigned short)(__float_as_uint(rem) >> 16);
}
__device__ __forceinline__ void pack2(float v0, float v1, unsigned& hw, unsigned& lw) {
  unsigned u0 = __float_as_uint(v0), u1 = __float_as_uint(v1);
  unsigned h0 = u0 & 0xFFFF0000u;
  unsigned h1 = u1 & 0xFFFF0000u;
  hw = (h0 >> 16) | h1;
  float r0 = v0 - __uint_as_float(h0);
  float r1 = v1 - __uint_as_float(h1);
  lw = (__float_as_uint(r0) >> 16) | (__float_as_uint(r1) & 0xFFFF0000u);
}

__device__ __forceinline__ float pair_kernel(
    float x0, float x1, float a1, float b1, float c1,
    float y0, float y1, float a2, float b2, float c2, float scale) {
  float det1 = a1 * b1 - c1 * c1;
  float det2 = a2 * b2 - c2 * c2;
  float s00 = a1 + a2, s11 = b1 + b2, s01 = c1 + c2;
  float sdet = s00 * s11 - s01 * s01;
  float d0 = x0 - y0, d1 = x1 - y1;
  float quad = s11 * d0 * d0 - 2.0f * s01 * d0 * d1 + s00 * d1 * d1;
  float Q = __fdividef(0.5f * quad, sdet);
  float x3 = 3.0f * fmaxf(Q, 1e-5f);
  float t = x3 * rsqrtf(x3);
  float C = 2.0f * sqrtf(sqrtf(det1)) * sqrtf(sqrtf(det2)) * rsqrtf(fmaxf(sdet, 1e-5f));
  return (1.0f + t) * __expf(-t) * C * scale;
}

// ---------------- A = K_nn + diag(var) ----------------
__global__ __launch_bounds__(256) void build_A(
    const float* __restrict__ xt, const float* __restrict__ pt,
    const float* __restrict__ var, const float* __restrict__ sp,
    float* __restrict__ A) {
  int idx = blockIdx.x * 256 + threadIdx.x;
  int b = idx / (kN * kN);
  int r = (idx / kN) % kN;
  int c = idx % kN;
  float scale = __expf(sp[0]);
  const float* x1 = xt + ((size_t)b * kN + r) * 2;
  const float* p1 = pt + ((size_t)b * kN + r) * 3;
  const float* x2 = xt + ((size_t)b * kN + c) * 2;
  const float* p2 = pt + ((size_t)b * kN + c) * 3;
  float k = pair_kernel(x1[0], x1[1], p1[0], p1[1], p1[2],
                        x2[0], x2[1], p2[0], p2[1], p2[2], scale);
  if (r == c) k += var[b * kN + r];
  A[(size_t)idx] = k;
}

__device__ __forceinline__ void tri_decode(int idx, int& ti, int& tj) {
  float f = sqrtf(8.0f * (float)idx + 1.0f);
  int t0 = (int)((f - 1.0f) * 0.5f);
  while (t0 * (t0 + 1) / 2 > idx) --t0;
  while ((t0 + 1) * (t0 + 2) / 2 <= idx) ++t0;
  ti = t0;
  tj = idx - t0 * (t0 + 1) / 2;
}

// ---------------- panel factor (128x128) + inverse, 256 threads, dynamic LDS ----------
// sh layout: At = sh+PAN_AT [128*132], Dt = sh+PAN_DT, Tt = sh+PAN_TT.
// If preStaged, caller has filled At (stride 132) with the diag block.
__device__ void panel_factor_256(float* __restrict__ sh, float* __restrict__ Ab,
                                 float* __restrict__ Db, unsigned short* __restrict__ Dhb,
                                 unsigned short* __restrict__ Dlb, int r0, int t,
                                 bool preStaged) {
  float* At = sh + PAN_AT;
  float* Dt = sh + PAN_DT;
  float* Tt = sh + PAN_TT;
  if (!preStaged) {
#pragma unroll
    for (int q = 0; q < 16; ++q) {
      int idx = t + 256 * q;
      int r = idx >> 5, c4 = idx & 31;
      *(float4*)&At[r * 132 + c4 * 4] = *(const float4*)&Ab[(size_t)(r0 + r) * kN + r0 + c4 * 4];
    }
  }
  __syncthreads();
  int wave = t >> 6, lane = t & 63;
  int row0 = lane, row1 = lane + 64;
  for (int kb = 0; kb < 16; ++kb) {
    int K0 = kb * 8;
    int Kp = K0 - 8;
    if (kb > 0) {
      if (wave == 0) {
        int rr = lane >> 3, cc = lane & 7;
        float s = 0.0f;
#pragma unroll
        for (int e = 0; e < 8; ++e)
          s += At[(K0 + rr) * 132 + Kp + e] * At[(K0 + cc) * 132 + Kp + e];
        At[(K0 + rr) * 132 + K0 + cc] -= s;
      } else {
        int n = 120 - 8 * kb;
        int nt = n >> 2;
        int ntt = nt * (nt + 1) / 2;
        int base = K0 + 8;
        for (int idx = t - 64; idx < ntt; idx += 192) {
          int ti, tj;
          tri_decode(idx, ti, tj);
          int i0 = base + ti * 4, j0 = base + tj * 4;
          float Li[4][8], Lj[4][8];
#pragma unroll
          for (int r = 0; r < 4; ++r) {
            *(float4*)&Li[r][0] = *(const float4*)&At[(i0 + r) * 132 + Kp];
            *(float4*)&Li[r][4] = *(const float4*)&At[(i0 + r) * 132 + Kp + 4];
            *(float4*)&Lj[r][0] = *(const float4*)&At[(j0 + r) * 132 + Kp];
            *(float4*)&Lj[r][4] = *(const float4*)&At[(j0 + r) * 132 + Kp + 4];
          }
#pragma unroll
          for (int r = 0; r < 4; ++r) {
            float4 cv = *(const float4*)&At[(i0 + r) * 132 + j0];
            float cc4[4] = {cv.x, cv.y, cv.z, cv.w};
#pragma unroll
            for (int c = 0; c < 4; ++c) {
              float s = 0.0f;
#pragma unroll
              for (int e = 0; e < 8; ++e) s += Li[r][e] * Lj[c][e];
              cc4[c] -= s;
            }
            float4 ov = {cc4[0], cc4[1], cc4[2], cc4[3]};
            *(float4*)&At[(i0 + r) * 132 + j0] = ov;
          }
        }
      }
    }
    __syncthreads();
    if (wave == 0) {
      float rA0[8], rA1[8];
      *(float4*)&rA0[0] = *(const float4*)&At[row0 * 132 + K0];
      *(float4*)&rA0[4] = *(const float4*)&At[row0 * 132 + K0 + 4];
      *(float4*)&rA1[0] = *(const float4*)&At[row1 * 132 + K0];
      *(float4*)&rA1[4] = *(const float4*)&At[row1 * 132 + K0 + 4];
      if (kb > 0) {
        float pA0[8], pA1[8];
        *(float4*)&pA0[0] = *(const float4*)&At[row0 * 132 + Kp];
        *(float4*)&pA0[4] = *(const float4*)&At[row0 * 132 + Kp + 4];
        *(float4*)&pA1[0] = *(const float4*)&At[row1 * 132 + Kp];
        *(float4*)&pA1[4] = *(const float4*)&At[row1 * 132 + Kp + 4];
#pragma unroll
        for (int j = 0; j < 8; ++j) {
          float s0 = 0.0f, s1 = 0.0f;
#pragma unroll
          for (int e = 0; e < 8; ++e) {
            float pj = At[(K0 + j) * 132 + Kp + e];
            s0 += pA0[e] * pj;
            s1 += pA1[e] * pj;
          }
          rA0[j] -= s0;
          rA1[j] -= s1;
        }
      }
      float L11[8][8], idg[8];
#pragma unroll
      for (int r = 0; r < 8; ++r) {
        *(float4*)&L11[r][0] = *(const float4*)&At[(K0 + r) * 132 + K0];
        *(float4*)&L11[r][4] = *(const float4*)&At[(K0 + r) * 132 + K0 + 4];
      }
#pragma unroll
      for (int c = 0; c < 8; ++c) {
        float d = sqrtf(L11[c][c]);
        float iv = 1.0f / d;
        idg[c] = iv;
        L11[c][c] = d;
#pragma unroll
        for (int i = c + 1; i < 8; ++i) L11[i][c] *= iv;
#pragma unroll
        for (int j = c + 1; j < 8; ++j)
#pragma unroll
          for (int i = j; i < 8; ++i) L11[i][j] -= L11[i][c] * L11[j][c];
      }
      if (row0 >= K0 + 8) {
#pragma unroll
        for (int c = 0; c < 8; ++c) {
          float s = rA0[c];
#pragma unroll
          for (int j = 0; j < c; ++j) s -= rA0[j] * L11[c][j];
          rA0[c] = s * idg[c];
        }
      } else if (row0 >= K0) {
#pragma unroll
        for (int rr = 0; rr < 8; ++rr)
          if (row0 - K0 == rr) {
#pragma unroll
            for (int e = 0; e < 8; ++e) rA0[e] = (e <= rr) ? L11[rr][e] : 0.0f;
          }
      }
      if (row1 >= K0 + 8) {
#pragma unroll
        for (int c = 0; c < 8; ++c) {
          float s = rA1[c];
#pragma unroll
          for (int j = 0; j < c; ++j) s -= rA1[j] * L11[c][j];
          rA1[c] = s * idg[c];
        }
      } else if (row1 >= K0) {
#pragma unroll
        for (int rr = 0; rr < 8; ++rr)
          if (row1 - K0 == rr) {
#pragma unroll
            for (int e = 0; e < 8; ++e) rA1[e] = (e <= rr) ? L11[rr][e] : 0.0f;
          }
      }
      if (row0 >= K0) {
        float4 v0 = {rA0[0], rA0[1], rA0[2], rA0[3]};
        float4 v1 = {rA0[4], rA0[5], rA0[6], rA0[7]};
        *(float4*)&At[row0 * 132 + K0] = v0;
        *(float4*)&At[row0 * 132 + K0 + 4] = v1;
      }
      if (row1 >= K0) {
        float4 v0 = {rA1[0], rA1[1], rA1[2], rA1[3]};
        float4 v1 = {rA1[4], rA1[5], rA1[6], rA1[7]};
        *(float4*)&At[row1 * 132 + K0] = v0;
        *(float4*)&At[row1 * 132 + K0 + 4] = v1;
      }
    }
    __syncthreads();
  }
  // triangular inverse: 32x32 base blocks (solution in registers)
  if (t < 128) {
    int q = t >> 5, c = t & 31, bse = q * 32;
    float x[32];
#pragma unroll
    for (int r = 0; r < 32; ++r) {
      float s = (r == c) ? 1.0f : 0.0f;
#pragma unroll
      for (int j = 0; j < 32; ++j)
        if (j < r) s -= At[(bse + r) * 132 + bse + j] * x[j];
      x[r] = (r < c) ? 0.0f : s / At[(bse + r) * 132 + bse + r];
    }
#pragma unroll
    for (int r = 0; r < 32; ++r) Dt[(bse + r) * 132 + bse + c] = x[r];
  }
  __syncthreads();
  {
    int rb_ = t >> 5, cl = t & 31;  // rb_ in [0,8)
    for (int s = 1; s <= 3; ++s) {
      for (int blk = 0; blk < 4 - s; ++blk) {
        int J = blk, I = J + s;
        for (int rr = 0; rr < 4; ++rr) {
          int r = rr * 8 + rb_;
          float sum = 0.0f;
          for (int K = J; K < I; ++K)
            for (int j = 0; j < 32; ++j)
              sum += At[(I * 32 + r) * 132 + K * 32 + j] * Dt[(K * 32 + j) * 132 + J * 32 + cl];
          Tt[blk * (32 * 33) + r * 33 + cl] = sum;
        }
      }
      __syncthreads();
      for (int blk = 0; blk < 4 - s; ++blk) {
        int J = blk, I = J + s;
        for (int rr = 0; rr < 4; ++rr) {
          int r = rr * 8 + rb_;
          float sum = 0.0f;
          for (int j = 0; j < 32; ++j)
            sum += Dt[(I * 32 + r) * 132 + I * 32 + j] * Tt[blk * (32 * 33) + j * 33 + cl];
          Dt[(I * 32 + r) * 132 + J * 32 + cl] = -sum;
        }
      }
      __syncthreads();
    }
  }
  // writebacks
#pragma unroll
  for (int q = 0; q < 16; ++q) {
    int jj = t + 256 * q;
    int r = jj >> 5, ch = jj & 31;
    int c0 = ch * 4;
    float4 v = *(const float4*)&At[r * 132 + c0];
    v.x = (c0 + 0 <= r) ? v.x : 0.0f;
    v.y = (c0 + 1 <= r) ? v.y : 0.0f;
    v.z = (c0 + 2 <= r) ? v.z : 0.0f;
    v.w = (c0 + 3 <= r) ? v.w : 0.0f;
    *(float4*)&Ab[(size_t)(r0 + r) * kN + r0 + c0] = v;
  }
#pragma unroll
  for (int q = 0; q < 16; ++q) {
    int jj = t + 256 * q;
    int r = jj >> 5, ch = jj & 31;
    int c0 = ch * 4;
    float4 v = *(const float4*)&Dt[r * 132 + c0];
    v.x = (c0 + 0 <= r) ? v.x : 0.0f;
    v.y = (c0 + 1 <= r) ? v.y : 0.0f;
    v.z = (c0 + 2 <= r) ? v.z : 0.0f;
    v.w = (c0 + 3 <= r) ? v.w : 0.0f;
    *(float4*)&Db[r * 128 + c0] = v;
    float vv[4] = {v.x, v.y, v.z, v.w};
    unsigned short hs[4], ls[4];
#pragma unroll
    for (int e = 0; e < 4; ++e) split_bf16(vv[e], hs[e], ls[e]);
    *(ushort4*)&Dhb[r * 128 + c0] = make_ushort4(hs[0], hs[1], hs[2], hs[3]);
    *(ushort4*)&Dlb[r * 128 + c0] = make_ushort4(ls[0], ls[1], ls[2], ls[3]);
  }
}

// ---------------- standalone panel launch (p=0) ----------------
__global__ __launch_bounds__(256, 1) void chol_panel0(float* __restrict__ A,
                                                      float* __restrict__ Dg,
                                                      unsigned short* __restrict__ Dh,
                                                      unsigned short* __restrict__ Dl, int p) {
  extern __shared__ float sh[];
  int b = blockIdx.x, t = threadIdx.x;
  panel_factor_256(sh, A + (size_t)b * kN * kN, Dg + (size_t)(b * 8 + p) * 16384,
                   Dh + (size_t)(b * 8 + p) * 16384, Dl + (size_t)(b * 8 + p) * 16384,
                   p * 128, t, false);
}

// ---------------- L21 = A21 * D_p^T (in place) + bf16(RN) of -L ----------------
__global__ __launch_bounds__(256) void chol_trsm(float* __restrict__ A,
                                                 const float* __restrict__ Dg,
                                                 unsigned short* __restrict__ Lh, int p) {
  __shared__ float At[128 * 129];
  __shared__ float Dt[128 * 129];
  int b = blockIdx.y, rb = blockIdx.x;
  int rs = (p + 1 + rb) * 128;
  float* Ab = A + (size_t)b * kN * kN;
  const float* Db = Dg + (size_t)(b * 8 + p) * 16384;
  int t = threadIdx.x;
  for (int q = 0; q < 64; ++q) {
    int li = t + 256 * q;
    int r = li >> 7, cc = li & 127;
    At[r * 129 + cc] = Ab[(size_t)(rs + r) * kN + p * 128 + cc];
    Dt[r * 129 + cc] = Db[r * 128 + cc];
  }
  __syncthreads();
  int tx = t & 15, ty = t >> 4;
  float acc[8][8] = {};
  for (int j = 0; j < 128; ++j) {
    float a[8], d[8];
#pragma unroll
    for (int q = 0; q < 8; ++q) a[q] = At[(ty * 8 + q) * 129 + j];
#pragma unroll
    for (int q = 0; q < 8; ++q) d[q] = Dt[(tx * 8 + q) * 129 + j];
#pragma unroll
    for (int qr = 0; qr < 8; ++qr)
#pragma unroll
      for (int qc = 0; qc < 8; ++qc) acc[qr][qc] = fmaf(a[qr], d[qc], acc[qr][qc]);
  }
#pragma unroll
  for (int qr = 0; qr < 8; ++qr)
#pragma unroll
    for (int qc = 0; qc < 8; ++qc) {
      float v = acc[qr][qc];
      Ab[(size_t)(rs + ty * 8 + qr) * kN + p * 128 + tx * 8 + qc] = v;
      size_t lo = ((size_t)b * kN + rs + ty * 8 + qr) * kN + p * 128 + tx * 8 + qc;
      Lh[lo] = b16rn(-v);
    }
}

// ---------------- fused syrk + lookahead panel(p+1) on pid==0 ----------------
__global__ __launch_bounds__(256, 1) void chol_syrk_panel(float* __restrict__ A,
                                                          float* __restrict__ Dg,
                                                          unsigned short* __restrict__ Dh,
                                                          unsigned short* __restrict__ Dl,
                                                          int p) {
  extern __shared__ float sh[];
  float* L1t = sh + SYR_L1;
  float* L2t = sh + SYR_L2;
  int b = blockIdx.y;
  int pid = blockIdx.x;
  int bi = 0;
  while ((bi + 1) * (bi + 2) / 2 <= pid) ++bi;
  int bj = pid - bi * (bi + 1) / 2;
  int rs1 = (p + 1 + bi) * 128, rs2 = (p + 1 + bj) * 128;
  float* Ab = A + (size_t)b * kN * kN;
  int t = threadIdx.x;
  for (int q = 0; q < 64; ++q) {
    int li = t + 256 * q;
    int r = li >> 7, cc = li & 127;
    L1t[r * 129 + cc] = Ab[(size_t)(rs1 + r) * kN + p * 128 + cc];
    L2t[r * 129 + cc] = Ab[(size_t)(rs2 + r) * kN + p * 128 + cc];
  }
  __syncthreads();
  int tx = t & 15, ty = t >> 4;
  float acc[8][8] = {};
  for (int j = 0; j < 128; ++j) {
    float a[8], d[8];
#pragma unroll
    for (int q = 0; q < 8; ++q) a[q] = L1t[(ty * 8 + q) * 129 + j];
#pragma unroll
    for (int q = 0; q < 8; ++q) d[q] = L2t[(tx * 8 + q) * 129 + j];
#pragma unroll
    for (int qr = 0; qr < 8; ++qr)
#pragma unroll
      for (int qc = 0; qc < 8; ++qc) acc[qr][qc] = fmaf(a[qr], d[qc], acc[qr][qc]);
  }
  if (pid != 0) {
#pragma unroll
    for (int qr = 0; qr < 8; ++qr)
#pragma unroll
      for (int qc = 0; qc < 8; ++qc) {
        size_t o = (size_t)(rs1 + ty * 8 + qr) * kN + rs2 + tx * 8 + qc;
        Ab[o] -= acc[qr][qc];
      }
    return;
  }
  // pid==0: pair (p+1, p+1). Build updated diag block directly in panel LDS (stride 132)
  // and factor panel p+1 in-launch (lookahead). Unfactored diag never written to global.
  __syncthreads();  // all GEMM reads of L1t/L2t done before overwrite
  float* At = sh + PAN_AT;
#pragma unroll
  for (int qr = 0; qr < 8; ++qr)
#pragma unroll
    for (int qc = 0; qc < 8; ++qc) {
      float ao = Ab[(size_t)(rs1 + ty * 8 + qr) * kN + rs2 + tx * 8 + qc];
      At[(ty * 8 + qr) * 132 + tx * 8 + qc] = ao - acc[qr][qc];
    }
  int pn = p + 1;
  panel_factor_256(sh, Ab, Dg + (size_t)(b * 8 + pn) * 16384,
                   Dh + (size_t)(b * 8 + pn) * 16384, Dl + (size_t)(b * 8 + pn) * 16384,
                   pn * 128, t, true);
}

// ---------------- z = L^-1 (y - mean), nlml (1024 thr, LDS-staged) ----------------
__global__ __launch_bounds__(1024) void solve_small(
    const float* __restrict__ A, const float* __restrict__ Dg,
    const float* __restrict__ y, const float* __restrict__ meanp,
    float* __restrict__ zbuf, float* __restrict__ out) {
  __shared__ float Ls[128 * 132];
  __shared__ __align__(16) float zs[1024];
  __shared__ float ts[128];
  __shared__ float part[128 * 9];
  __shared__ float red[1024];
  int b = blockIdx.x, t = threadIdx.x;
  int row = t & 127, g = t >> 7;
  const float* Ab = A + (size_t)b * kN * kN;
  float mv = meanp[b];
  zs[t] = y[b * kN + t] - mv;
  __syncthreads();
  for (int i = 0; i < 8; ++i) {
    float ps = 0.0f;
    for (int k = 0; k < i; ++k) {
#pragma unroll
      for (int q = 0; q < 4; ++q) {
        int li = t + 1024 * q;
        int r = li >> 5, c4 = li & 31;
        *(float4*)&Ls[r * 132 + c4 * 4] =
            *(const float4*)&Ab[(size_t)(i * 128 + r) * kN + k * 128 + c4 * 4];
      }
      __syncthreads();
      const float* Lr = &Ls[row * 132 + g * 16];
      const float* zk = &zs[k * 128 + g * 16];
#pragma unroll
      for (int c = 0; c < 16; c += 4) {
        float4 lv = *(const float4*)&Lr[c];
        float4 zv = *(const float4*)&zk[c];
        ps += lv.x * zv.x + lv.y * zv.y + lv.z * zv.z + lv.w * zv.w;
      }
      __syncthreads();
    }
    part[row * 9 + g] = ps;
    {
      const float* Db = Dg + (size_t)(b * 8 + i) * 16384;
#pragma unroll
      for (int q = 0; q < 4; ++q) {
        int li = t + 1024 * q;
        int r = li >> 5, c4 = li & 31;
        *(float4*)&Ls[r * 132 + c4 * 4] = *(const float4*)&Db[r * 128 + c4 * 4];
      }
    }
    __syncthreads();
    if (g == 0) {
      float acc = zs[i * 128 + row];
#pragma unroll
      for (int gg = 0; gg < 8; ++gg) acc -= part[row * 9 + gg];
      ts[row] = acc;
    }
    __syncthreads();
    float s = 0.0f;
    int c0 = g * 16, c1 = min(c0 + 16, row + 1);
    for (int c = c0; c < c1; ++c) s += Ls[row * 132 + c] * ts[c];
    part[row * 9 + g] = s;
    __syncthreads();
    if (g == 0) {
      float zv = 0.0f;
#pragma unroll
      for (int gg = 0; gg < 8; ++gg) zv += part[row * 9 + gg];
      zs[i * 128 + row] = zv;
    }
    __syncthreads();
  }
  red[t] = zs[t] * zs[t];
  __syncthreads();
  for (int s = 512; s > 0; s >>= 1) {
    if (t < s) red[t] += red[t + s];
    __syncthreads();
  }
  float dfs = red[0];
  __syncthreads();
  red[t] = logf(Ab[(size_t)t * kN + t]);
  __syncthreads();
  for (int s = 512; s > 0; s >>= 1) {
    if (t < s) red[t] += red[t + s];
    __syncthreads();
  }
  if (t == 0)
    out[2 * kB * kM + b] = 0.5f * dfs + red[0] + 0.5f * 1024.0f * logf(6.283185307179586f);
  zbuf[b * kN + t] = zs[t];
}

// ---------------- fused MFMA solve: K build + w = L^-1 K + outputs ----------------
// Th/Tl stride 136 shorts (68 words = 4 mod 32 -> 2-way = free quarter-wave access).
__global__ __launch_bounds__(256, 2) void fused_mfma(
    const unsigned short* __restrict__ Lh,
    const unsigned short* __restrict__ Dh, const unsigned short* __restrict__ Dl,
    const float* __restrict__ xt, const float* __restrict__ pt,
    const float* __restrict__ xs, const float* __restrict__ ps,
    const float* __restrict__ sp, const float* __restrict__ meanp,
    const float* __restrict__ zbuf, float* __restrict__ out) {
  __shared__ unsigned short Th[32 * 136];
  __shared__ unsigned short Tl[32 * 136];
  __shared__ float trp[128 * 6];
  __shared__ float tp[32 * 6];
  __shared__ float zs[128];
  __shared__ float red[32 * 16 * 2];
  int bid = blockIdx.x;
  int xcd = bid & 7;
  int b = xcd >> 2;
  int mt = (xcd & 3) * 128 + (bid >> 3);
  int t = threadIdx.x;
  int lane = t & 63, wave = t >> 6;
  int lrow = lane & 15, kgrp = lane >> 4;
  float scale = __expf(sp[0]);
  if (t < 32) {
    int mg = mt * 32 + t;
    float x0 = xs[((size_t)b * kM + mg) * 2 + 0];
    float x1 = xs[((size_t)b * kM + mg) * 2 + 1];
    float a = ps[((size_t)b * kM + mg) * 3 + 0];
    float bb = ps[((size_t)b * kM + mg) * 3 + 1];
    float c = ps[((size_t)b * kM + mg) * 3 + 2];
    float det2 = a * bb - c * c;
    tp[t * 6 + 0] = x0; tp[t * 6 + 1] = x1; tp[t * 6 + 2] = a;
    tp[t * 6 + 3] = bb; tp[t * 6 + 4] = c; tp[t * 6 + 5] = sqrtf(sqrtf(det2));
  }
  floatx4 W[8][2][2];
#pragma unroll
  for (int i = 0; i < 8; ++i)
#pragma unroll
    for (int rf = 0; rf < 2; ++rf)
#pragma unroll
      for (int cf = 0; cf < 2; ++cf) W[i][rf][cf] = (floatx4){0.f, 0.f, 0.f, 0.f};
  float pma[2] = {0.f, 0.f}, s2a[2] = {0.f, 0.f};

#define FUSED_K_STEP(KC)                                                                   \
  {                                                                                        \
    constexpr int k = (KC);                                                                \
    __syncthreads();                                                                       \
    if (t < 128) {                                                                         \
      size_t n = (size_t)b * kN + k * 128 + t;                                             \
      float x0 = xt[n * 2 + 0];                                                            \
      float x1 = xt[n * 2 + 1];                                                            \
      float a = pt[n * 3 + 0];                                                             \
      float bb = pt[n * 3 + 1];                                                            \
      float c = pt[n * 3 + 2];                                                             \
      float det1 = a * bb - c * c;                                                         \
      trp[t * 6 + 0] = x0; trp[t * 6 + 1] = x1; trp[t * 6 + 2] = a;                        \
      trp[t * 6 + 3] = bb; trp[t * 6 + 4] = c;                                             \
      trp[t * 6 + 5] = 2.0f * scale * sqrtf(sqrtf(det1));                                  \
      zs[t] = zbuf[n];                                                                     \
    }                                                                                      \
    __syncthreads();                                                                       \
    _Pragma("unroll")                                                                      \
    for (int rf = 0; rf < 2; ++rf) {                                                       \
      int n0 = wave * 32 + rf * 16 + kgrp * 4;                                             \
      float nx0[4], nx1[4], na[4], nb[4], nc[4], nc1[4];                                   \
      _Pragma("unroll")                                                                    \
      for (int r = 0; r < 4; ++r) {                                                        \
        int n = n0 + r;                                                                    \
        nx0[r] = trp[n * 6 + 0]; nx1[r] = trp[n * 6 + 1]; na[r] = trp[n * 6 + 2];          \
        nb[r] = trp[n * 6 + 3]; nc[r] = trp[n * 6 + 4]; nc1[r] = trp[n * 6 + 5];           \
      }                                                                                    \
      _Pragma("unroll")                                                                    \
      for (int cf = 0; cf < 2; ++cf) {                                                     \
        int m = cf * 16 + lrow;                                                            \
        float mx0 = tp[m * 6 + 0], mx1 = tp[m * 6 + 1], ma = tp[m * 6 + 2];                \
        float mb = tp[m * 6 + 3], mc = tp[m * 6 + 4], mq = tp[m * 6 + 5];                  \
        float Tv[4];                                                                       \
        _Pragma("unroll")                                                                  \
        for (int r = 0; r < 4; ++r) {                                                      \
          float s00 = na[r] + ma, s11 = nb[r] + mb, s01 = nc[r] + mc;                      \
          float sdet = s00 * s11 - s01 * s01;                                              \
          float d0 = nx0[r] - mx0, d1 = nx1[r] - mx1;                                      \
          float quad = s11 * d0 * d0 - 2.0f * s01 * d0 * d1 + s00 * d1 * d1;               \
          float Q = __fdividef(0.5f * quad, sdet);                                         \
          float x3 = 3.0f * fmaxf(Q, 1e-5f);                                               \
          float tt = x3 * rsqrtf(x3);                                                      \
          float Kv = (1.0f + tt) * __expf(-tt) * nc1[r] * (mq * rsqrtf(fmaxf(sdet, 1e-5f))); \
          Tv[r] = Kv + W[k][rf][cf][r];                                                    \
        }                                                                                  \
        unsigned hw[2], lw[2];                                                             \
        pack2(Tv[0], Tv[1], hw[0], lw[0]);                                                 \
        pack2(Tv[2], Tv[3], hw[1], lw[1]);                                                 \
        int off = m * 136 + n0;                                                            \
        *(uint2*)&Th[off] = make_uint2(hw[0], hw[1]);                                      \
        *(uint2*)&Tl[off] = make_uint2(lw[0], lw[1]);                                      \
      }                                                                                    \
    }                                                                                      \
    __syncthreads();                                                                       \
    floatx4 wk[2][2];                                                                      \
    _Pragma("unroll")                                                                      \
    for (int rf = 0; rf < 2; ++rf)                                                         \
      _Pragma("unroll")                                                                    \
      for (int cf = 0; cf < 2; ++cf) wk[rf][cf] = (floatx4){0.f, 0.f, 0.f, 0.f};           \
    {                                                                                      \
      const unsigned short* Dhb = Dh + (size_t)(b * 8 + k) * 16384;                        \
      const unsigned short* Dlb = Dl + (size_t)(b * 8 + k) * 16384;                        \
      _Pragma("unroll")                                                                    \
      for (int ks = 0; ks < 4; ++ks) {                                                     \
        short8v bh[2], bl[2];                                                              \
        _Pragma("unroll")                                                                  \
        for (int cf = 0; cf < 2; ++cf) {                                                   \
          int boff = (cf * 16 + lrow) * 136 + ks * 32 + kgrp * 8;                          \
          bh[cf] = *(const short8v*)&Th[boff];                                             \
          bl[cf] = *(const short8v*)&Tl[boff];                                             \
        }                                                                                  \
        short8v ah[2], al[2];                                                              \
        _Pragma("unroll")                                                                  \
        for (int rf = 0; rf < 2; ++rf) {                                                   \
          size_t aoff = (size_t)(wave * 32 + rf * 16 + lrow) * 128 + ks * 32 + kgrp * 8;   \
          ah[rf] = *(const short8v*)&Dhb[aoff];                                            \
          al[rf] = *(const short8v*)&Dlb[aoff];                                            \
        }                                                                                  \
        _Pragma("unroll")                                                                  \
        for (int rf = 0; rf < 2; ++rf)                                                     \
          _Pragma("unroll")                                                                \
          for (int cf = 0; cf < 2; ++cf) {                                                 \
            wk[rf][cf] = __builtin_amdgcn_mfma_f32_16x16x32_bf16(ah[rf], bh[cf], wk[rf][cf], 0, 0, 0); \
            wk[rf][cf] = __builtin_amdgcn_mfma_f32_16x16x32_bf16(ah[rf], bl[cf], wk[rf][cf], 0, 0, 0); \
            wk[rf][cf] = __builtin_amdgcn_mfma_f32_16x16x32_bf16(al[rf], bh[cf], wk[rf][cf], 0, 0, 0); \
          }                                                                                \
      }                                                                                    \
    }                                                                                      \
    __syncthreads();                                                                       \
    _Pragma("unroll")                                                                      \
    for (int rf = 0; rf < 2; ++rf) {                                                       \
      int n0 = wave * 32 + rf * 16 + kgrp * 4;                                             \
      _Pragma("unroll")                                                                    \
      for (int cf = 0; cf < 2; ++cf) {                                                     \
        int m = cf * 16 + lrow;                                                            \
        float wv[4];                                                                       \
        _Pragma("unroll")                                                                  \
        for (int r = 0; r < 4; ++r) {                                                      \
          wv[r] = wk[rf][cf][r];                                                           \
          pma[cf] = fmaf(wv[r], zs[n0 + r], pma[cf]);                                      \
          s2a[cf] = fmaf(wv[r], wv[r], s2a[cf]);                                           \
        }                                                                                  \
        unsigned hw[2], lw[2];                                                             \
        pack2(wv[0], wv[1], hw[0], lw[0]);                                                 \
        pack2(wv[2], wv[3], hw[1], lw[1]);                                                 \
        int off = m * 136 + n0;                                                            \
        *(uint2*)&Th[off] = make_uint2(hw[0], hw[1]);                                      \
        *(uint2*)&Tl[off] = make_uint2(lw[0], lw[1]);                                      \
      }                                                                                    \
    }                                                                                      \
    __syncthreads();                                                                       \
    __builtin_amdgcn_s_setprio(1);                                                         \
    _Pragma("unroll")                                                                      \
    for (int ks = 0; ks < 4; ++ks) {                                                       \
      short8v bh[2], bl[2];                                                                \
      _Pragma("unroll")                                                                    \
      for (int cf = 0; cf < 2; ++cf) {                                                     \
        int boff = (cf * 16 + lrow) * 136 + ks * 32 + kgrp * 8;                            \
        bh[cf] = *(const short8v*)&Th[boff];                                               \
        bl[cf] = *(const short8v*)&Tl[boff];                                               \
      }                                                                                    \
      _Pragma("unroll")                                                                    \
      for (int i = k + 1; i < 8; ++i) {                                                    \
        short8v ah[2];                                                                     \
        _Pragma("unroll")                                                                  \
        for (int rf = 0; rf < 2; ++rf) {                                                   \
          size_t ro = (size_t)b * kN + i * 128 + wave * 32 + rf * 16 + lrow;               \
          size_t aoff = ro * kN + k * 128 + ks * 32 + kgrp * 8;                            \
          ah[rf] = *(const short8v*)&Lh[aoff];                                             \
        }                                                                                  \
        _Pragma("unroll")                                                                  \
        for (int rf = 0; rf < 2; ++rf)                                                     \
          _Pragma("unroll")                                                                \
          for (int cf = 0; cf < 2; ++cf) {                                                 \
            W[i][rf][cf] = __builtin_amdgcn_mfma_f32_16x16x32_bf16(ah[rf], bh[cf], W[i][rf][cf], 0, 0, 0); \
            W[i][rf][cf] = __builtin_amdgcn_mfma_f32_16x16x32_bf16(ah[rf], bl[cf], W[i][rf][cf], 0, 0, 0); \
          }                                                                                \
      }                                                                                    \
    }                                                                                      \
    __builtin_amdgcn_s_setprio(0);                                                         \
  }

  FUSED_K_STEP(0)
  FUSED_K_STEP(1)
  FUSED_K_STEP(2)
  FUSED_K_STEP(3)
  FUSED_K_STEP(4)
  FUSED_K_STEP(5)
  FUSED_K_STEP(6)
  FUSED_K_STEP(7)
#undef FUSED_K_STEP

  __syncthreads();
#pragma unroll
  for (int cf = 0; cf < 2; ++cf) {
    int m = cf * 16 + lrow;
    red[m * 16 + wave * 4 + kgrp] = pma[cf];
    red[512 + m * 16 + wave * 4 + kgrp] = s2a[cf];
  }
  __syncthreads();
  if (t < 32) {
    float pm = 0.f, s2 = 0.f;
#pragma unroll
    for (int j = 0; j < 16; ++j) {
      pm += red[t * 16 + j];
      s2 += red[512 + t * 16 + j];
    }
    int mg = mt * 32 + t;
    float a = tp[t * 6 + 2], bb = tp[t * 6 + 3], c = tp[t * 6 + 4];
    float det = a * bb - c * c;
    float C = 2.0f * sqrtf(det) * rsqrtf(fmaxf(4.0f * det, 1e-5f));
    float t0 = kSqrt3 * sqrtf(1e-5f);
    float mat = (1.0f + t0) * __expf(-t0);
    float kd = C * mat * scale;
    out[b * kM + mg] = meanp[b] + pm;
    out[kB * kM + b * kM + mg] = kd - s2;
  }
}

extern "C" void kernel_launch(void* const* d_in, const int* in_sizes, int n_in,
                              void* d_out, int out_size, void* d_ws, size_t ws_size,
                              hipStream_t stream) {
  const float* xt = (const float*)d_in[0];
  const float* pt = (const float*)d_in[1];
  const float* xs = (const float*)d_in[2];
  const float* ps = (const float*)d_in[3];
  const float* y = (const float*)d_in[4];
  const float* var = (const float*)d_in[5];
  const float* meanp = (const float*)d_in[6];
  const float* sp = (const float*)d_in[7];
  float* out = (float*)d_out;
  char* ws = (char*)d_ws;
  if (ws_size < WS_BYTES) return;

  float* A = (float*)(ws + A_OFF);
  float* Dg = (float*)(ws + DG_OFF);
  float* zbuf = (float*)(ws + Z_OFF);
  unsigned short* Lh = (unsigned short*)(ws + LH_OFF);
  unsigned short* Dh = (unsigned short*)(ws + DH_OFF);
  unsigned short* Dl = (unsigned short*)(ws + DL_OFF);

  const size_t panLds = PAN_FLOATS * sizeof(float);  // 147840 B

  build_A<<<(kB * kN * kN) / 256, 256, 0, stream>>>(xt, pt, var, sp, A);
  chol_panel0<<<kB, 256, panLds, stream>>>(A, Dg, Dh, Dl, 0);
  for (int p = 0; p < 7; ++p) {
    int nt = 7 - p;
    chol_trsm<<<dim3(nt, kB), 256, 0, stream>>>(A, Dg, Lh, p);
    int npairs = nt * (nt + 1) / 2;
    chol_syrk_panel<<<dim3(npairs, kB), 256, panLds, stream>>>(A, Dg, Dh, Dl, p);
  }
  solve_small<<<kB, 1024, 0, stream>>>(A, Dg, y, meanp, zbuf, out);
  fused_mfma<<<kB * 512, 256, 0, stream>>>(Lh, Dh, Dl, xt, pt, xs, ps,
                                           sp, meanp, zbuf, out);
}

// Round 10
// 1243.279 us; speedup vs baseline: 1.0899x; 1.0899x over previous
//
#include <hip/hip_runtime.h>
#include <math.h>

namespace {
constexpr int kB = 2;
constexpr int kN = 1024;
constexpr int kM = 16384;
constexpr float kSqrt3 = 1.7320508075688772f;

// workspace layout (bytes)
constexpr size_t A_BYTES = (size_t)kB * kN * kN * 4;
constexpr size_t DG_BYTES = (size_t)kB * 8 * 128 * 128 * 4;
constexpr size_t Z_BYTES = (size_t)kB * kN * 4;
constexpr size_t LH_BYTES = (size_t)kB * kN * kN * 2;
constexpr size_t DH_BYTES = (size_t)kB * 8 * 128 * 128 * 2;
constexpr size_t A_OFF = 0;
constexpr size_t DG_OFF = A_OFF + A_BYTES;
constexpr size_t Z_OFF = DG_OFF + DG_BYTES;
constexpr size_t LH_OFF = Z_OFF + Z_BYTES;
constexpr size_t LL_OFF = LH_OFF + LH_BYTES;   // (unused)
constexpr size_t DH_OFF = LL_OFF + LH_BYTES;
constexpr size_t DL_OFF = DH_OFF + DH_BYTES;
constexpr size_t WS_BYTES = DL_OFF + DH_BYTES;

// dynamic-LDS float offsets
constexpr int PAN_AT = 0;            // 128*132
constexpr int PAN_DT = 16896;        // 128*132
constexpr int PAN_TT = 33792;        // 3*32*33
constexpr int PAN_FLOATS = 36960;    // 147840 bytes
constexpr int SYR_L1 = 0;            // 128*129
constexpr int SYR_L2 = 16512;        // 128*129
}  // namespace

typedef __attribute__((ext_vector_type(8))) short short8v;
typedef __attribute__((ext_vector_type(4))) float floatx4;

__device__ __forceinline__ float b16f(unsigned short h) {
  return __uint_as_float(((unsigned)h) << 16);
}
__device__ __forceinline__ unsigned short b16rn(float x) {
  unsigned u = __float_as_uint(x);
  unsigned r = u + 0x7FFFu + ((u >> 16) & 1u);
  return (unsigned short)(r >> 16);
}
__device__ __forceinline__ void split_bf16(float x, unsigned short& h, unsigned short& l) {
  unsigned u = __float_as_uint(x);
  h = (unsigned short)(u >> 16);
  float rem = x - b16f(h);
  l = (unsigned short)(__float_as_uint(rem) >> 16);
}
__device__ __forceinline__ void pack2(float v0, float v1, unsigned& hw, unsigned& lw) {
  unsigned u0 = __float_as_uint(v0), u1 = __float_as_uint(v1);
  unsigned h0 = u0 & 0xFFFF0000u;
  unsigned h1 = u1 & 0xFFFF0000u;
  hw = (h0 >> 16) | h1;
  float r0 = v0 - __uint_as_float(h0);
  float r1 = v1 - __uint_as_float(h1);
  lw = (__float_as_uint(r0) >> 16) | (__float_as_uint(r1) & 0xFFFF0000u);
}

__device__ __forceinline__ float pair_kernel(
    float x0, float x1, float a1, float b1, float c1,
    float y0, float y1, float a2, float b2, float c2, float scale) {
  float det1 = a1 * b1 - c1 * c1;
  float det2 = a2 * b2 - c2 * c2;
  float s00 = a1 + a2, s11 = b1 + b2, s01 = c1 + c2;
  float sdet = s00 * s11 - s01 * s01;
  float d0 = x0 - y0, d1 = x1 - y1;
  float quad = s11 * d0 * d0 - 2.0f * s01 * d0 * d1 + s00 * d1 * d1;
  float Q = __fdividef(0.5f * quad, sdet);
  float x3 = 3.0f * fmaxf(Q, 1e-5f);
  float t = x3 * rsqrtf(x3);
  float C = 2.0f * sqrtf(sqrtf(det1)) * sqrtf(sqrtf(det2)) * rsqrtf(fmaxf(sdet, 1e-5f));
  return (1.0f + t) * __expf(-t) * C * scale;
}

// ---------------- A = K_nn + diag(var) ----------------
__global__ __launch_bounds__(256) void build_A(
    const float* __restrict__ xt, const float* __restrict__ pt,
    const float* __restrict__ var, const float* __restrict__ sp,
    float* __restrict__ A) {
  int idx = blockIdx.x * 256 + threadIdx.x;
  int b = idx / (kN * kN);
  int r = (idx / kN) % kN;
  int c = idx % kN;
  float scale = __expf(sp[0]);
  const float* x1 = xt + ((size_t)b * kN + r) * 2;
  const float* p1 = pt + ((size_t)b * kN + r) * 3;
  const float* x2 = xt + ((size_t)b * kN + c) * 2;
  const float* p2 = pt + ((size_t)b * kN + c) * 3;
  float k = pair_kernel(x1[0], x1[1], p1[0], p1[1], p1[2],
                        x2[0], x2[1], p2[0], p2[1], p2[2], scale);
  if (r == c) k += var[b * kN + r];
  A[(size_t)idx] = k;
}

__device__ __forceinline__ void tri_decode(int idx, int& ti, int& tj) {
  float f = sqrtf(8.0f * (float)idx + 1.0f);
  int t0 = (int)((f - 1.0f) * 0.5f);
  while (t0 * (t0 + 1) / 2 > idx) --t0;
  while ((t0 + 1) * (t0 + 2) / 2 <= idx) ++t0;
  ti = t0;
  tj = idx - t0 * (t0 + 1) / 2;
}

// ---------------- panel factor (128x128), 1024 threads, dynamic LDS ----------------
// sh: At = sh+PAN_AT [128*132], Dt = sh+PAN_DT, Tt = sh+PAN_TT.
// If preStaged, caller filled At (stride 132).
__device__ void panel_factor_1024(float* __restrict__ sh, float* __restrict__ Ab,
                                  float* __restrict__ Db, unsigned short* __restrict__ Dhb,
                                  unsigned short* __restrict__ Dlb, int r0, int t,
                                  bool preStaged) {
  float* At = sh + PAN_AT;
  float* Dt = sh + PAN_DT;
  float* Tt = sh + PAN_TT;
  if (!preStaged) {
#pragma unroll
    for (int q = 0; q < 4; ++q) {
      int idx = t + 1024 * q;
      int r = idx >> 5, c4 = idx & 31;
      *(float4*)&At[r * 132 + c4 * 4] = *(const float4*)&Ab[(size_t)(r0 + r) * kN + r0 + c4 * 4];
    }
  }
  __syncthreads();
  int wave = t >> 6, lane = t & 63;
  int row0 = lane, row1 = lane + 64;
  for (int kb = 0; kb < 16; ++kb) {
    int K0 = kb * 8;
    int Kp = K0 - 8;
    if (kb > 0) {
      if (wave == 0) {
        int rr = lane >> 3, cc = lane & 7;
        float s = 0.0f;
#pragma unroll
        for (int e = 0; e < 8; ++e)
          s += At[(K0 + rr) * 132 + Kp + e] * At[(K0 + cc) * 132 + Kp + e];
        At[(K0 + rr) * 132 + K0 + cc] -= s;
      } else {
        int n = 120 - 8 * kb;
        int nt = n >> 2;
        int ntt = nt * (nt + 1) / 2;
        int base = K0 + 8;
        for (int idx = t - 64; idx < ntt; idx += 960) {
          int ti, tj;
          tri_decode(idx, ti, tj);
          int i0 = base + ti * 4, j0 = base + tj * 4;
          float Li[4][8], Lj[4][8];
#pragma unroll
          for (int r = 0; r < 4; ++r) {
            *(float4*)&Li[r][0] = *(const float4*)&At[(i0 + r) * 132 + Kp];
            *(float4*)&Li[r][4] = *(const float4*)&At[(i0 + r) * 132 + Kp + 4];
            *(float4*)&Lj[r][0] = *(const float4*)&At[(j0 + r) * 132 + Kp];
            *(float4*)&Lj[r][4] = *(const float4*)&At[(j0 + r) * 132 + Kp + 4];
          }
#pragma unroll
          for (int r = 0; r < 4; ++r) {
            float4 cv = *(const float4*)&At[(i0 + r) * 132 + j0];
            float cc4[4] = {cv.x, cv.y, cv.z, cv.w};
#pragma unroll
            for (int c = 0; c < 4; ++c) {
              float s = 0.0f;
#pragma unroll
              for (int e = 0; e < 8; ++e) s += Li[r][e] * Lj[c][e];
              cc4[c] -= s;
            }
            float4 ov = {cc4[0], cc4[1], cc4[2], cc4[3]};
            *(float4*)&At[(i0 + r) * 132 + j0] = ov;
          }
        }
      }
    }
    __syncthreads();
    if (wave == 0) {
      float rA0[8], rA1[8];
      *(float4*)&rA0[0] = *(const float4*)&At[row0 * 132 + K0];
      *(float4*)&rA0[4] = *(const float4*)&At[row0 * 132 + K0 + 4];
      *(float4*)&rA1[0] = *(const float4*)&At[row1 * 132 + K0];
      *(float4*)&rA1[4] = *(const float4*)&At[row1 * 132 + K0 + 4];
      if (kb > 0) {
        float pA0[8], pA1[8];
        *(float4*)&pA0[0] = *(const float4*)&At[row0 * 132 + Kp];
        *(float4*)&pA0[4] = *(const float4*)&At[row0 * 132 + Kp + 4];
        *(float4*)&pA1[0] = *(const float4*)&At[row1 * 132 + Kp];
        *(float4*)&pA1[4] = *(const float4*)&At[row1 * 132 + Kp + 4];
#pragma unroll
        for (int j = 0; j < 8; ++j) {
          float s0 = 0.0f, s1 = 0.0f;
#pragma unroll
          for (int e = 0; e < 8; ++e) {
            float pj = At[(K0 + j) * 132 + Kp + e];
            s0 += pA0[e] * pj;
            s1 += pA1[e] * pj;
          }
          rA0[j] -= s0;
          rA1[j] -= s1;
        }
      }
      float L11[8][8], idg[8];
#pragma unroll
      for (int r = 0; r < 8; ++r) {
        *(float4*)&L11[r][0] = *(const float4*)&At[(K0 + r) * 132 + K0];
        *(float4*)&L11[r][4] = *(const float4*)&At[(K0 + r) * 132 + K0 + 4];
      }
#pragma unroll
      for (int c = 0; c < 8; ++c) {
        float d = sqrtf(L11[c][c]);
        float iv = 1.0f / d;
        idg[c] = iv;
        L11[c][c] = d;
#pragma unroll
        for (int i = c + 1; i < 8; ++i) L11[i][c] *= iv;
#pragma unroll
        for (int j = c + 1; j < 8; ++j)
#pragma unroll
          for (int i = j; i < 8; ++i) L11[i][j] -= L11[i][c] * L11[j][c];
      }
      if (row0 >= K0 + 8) {
#pragma unroll
        for (int c = 0; c < 8; ++c) {
          float s = rA0[c];
#pragma unroll
          for (int j = 0; j < c; ++j) s -= rA0[j] * L11[c][j];
          rA0[c] = s * idg[c];
        }
      } else if (row0 >= K0) {
#pragma unroll
        for (int rr = 0; rr < 8; ++rr)
          if (row0 - K0 == rr) {
#pragma unroll
            for (int e = 0; e < 8; ++e) rA0[e] = (e <= rr) ? L11[rr][e] : 0.0f;
          }
      }
      if (row1 >= K0 + 8) {
#pragma unroll
        for (int c = 0; c < 8; ++c) {
          float s = rA1[c];
#pragma unroll
          for (int j = 0; j < c; ++j) s -= rA1[j] * L11[c][j];
          rA1[c] = s * idg[c];
        }
      } else if (row1 >= K0) {
#pragma unroll
        for (int rr = 0; rr < 8; ++rr)
          if (row1 - K0 == rr) {
#pragma unroll
            for (int e = 0; e < 8; ++e) rA1[e] = (e <= rr) ? L11[rr][e] : 0.0f;
          }
      }
      if (row0 >= K0) {
        float4 v0 = {rA0[0], rA0[1], rA0[2], rA0[3]};
        float4 v1 = {rA0[4], rA0[5], rA0[6], rA0[7]};
        *(float4*)&At[row0 * 132 + K0] = v0;
        *(float4*)&At[row0 * 132 + K0 + 4] = v1;
      }
      if (row1 >= K0) {
        float4 v0 = {rA1[0], rA1[1], rA1[2], rA1[3]};
        float4 v1 = {rA1[4], rA1[5], rA1[6], rA1[7]};
        *(float4*)&At[row1 * 132 + K0] = v0;
        *(float4*)&At[row1 * 132 + K0 + 4] = v1;
      }
    }
    __syncthreads();
  }
  // triangular inverse: 32x32 base blocks (solution in registers)
  if (t < 128) {
    int q = t >> 5, c = t & 31, bse = q * 32;
    float x[32];
#pragma unroll
    for (int r = 0; r < 32; ++r) {
      float s = (r == c) ? 1.0f : 0.0f;
#pragma unroll
      for (int j = 0; j < 32; ++j)
        if (j < r) s -= At[(bse + r) * 132 + bse + j] * x[j];
      x[r] = (r < c) ? 0.0f : s / At[(bse + r) * 132 + bse + r];
    }
#pragma unroll
    for (int r = 0; r < 32; ++r) Dt[(bse + r) * 132 + bse + c] = x[r];
  }
  __syncthreads();
  {
    int r = t >> 5, cl = t & 31;
    for (int s = 1; s <= 3; ++s) {
      for (int blk = 0; blk < 4 - s; ++blk) {
        int J = blk, I = J + s;
        float sum = 0.0f;
        for (int K = J; K < I; ++K)
          for (int j = 0; j < 32; ++j)
            sum += At[(I * 32 + r) * 132 + K * 32 + j] * Dt[(K * 32 + j) * 132 + J * 32 + cl];
        Tt[blk * (32 * 33) + r * 33 + cl] = sum;
      }
      __syncthreads();
      for (int blk = 0; blk < 4 - s; ++blk) {
        int J = blk, I = J + s;
        float sum = 0.0f;
        for (int j = 0; j < 32; ++j)
          sum += Dt[(I * 32 + r) * 132 + I * 32 + j] * Tt[blk * (32 * 33) + j * 33 + cl];
        Dt[(I * 32 + r) * 132 + J * 32 + cl] = -sum;
      }
      __syncthreads();
    }
  }
  // writebacks
#pragma unroll
  for (int q = 0; q < 4; ++q) {
    int jj = t + 1024 * q;
    int r = jj >> 5, ch = jj & 31;
    int c0 = ch * 4;
    float4 v = *(const float4*)&At[r * 132 + c0];
    v.x = (c0 + 0 <= r) ? v.x : 0.0f;
    v.y = (c0 + 1 <= r) ? v.y : 0.0f;
    v.z = (c0 + 2 <= r) ? v.z : 0.0f;
    v.w = (c0 + 3 <= r) ? v.w : 0.0f;
    *(float4*)&Ab[(size_t)(r0 + r) * kN + r0 + c0] = v;
  }
#pragma unroll
  for (int q = 0; q < 4; ++q) {
    int jj = t + 1024 * q;
    int r = jj >> 5, ch = jj & 31;
    int c0 = ch * 4;
    float4 v = *(const float4*)&Dt[r * 132 + c0];
    v.x = (c0 + 0 <= r) ? v.x : 0.0f;
    v.y = (c0 + 1 <= r) ? v.y : 0.0f;
    v.z = (c0 + 2 <= r) ? v.z : 0.0f;
    v.w = (c0 + 3 <= r) ? v.w : 0.0f;
    *(float4*)&Db[r * 128 + c0] = v;
    float vv[4] = {v.x, v.y, v.z, v.w};
    unsigned short hs[4], ls[4];
#pragma unroll
    for (int e = 0; e < 4; ++e) split_bf16(vv[e], hs[e], ls[e]);
    *(ushort4*)&Dhb[r * 128 + c0] = make_ushort4(hs[0], hs[1], hs[2], hs[3]);
    *(ushort4*)&Dlb[r * 128 + c0] = make_ushort4(ls[0], ls[1], ls[2], ls[3]);
  }
}

// ---------------- standalone panel launch (p=0) ----------------
__global__ __launch_bounds__(1024, 1) void chol_panel0(float* __restrict__ A,
                                                       float* __restrict__ Dg,
                                                       unsigned short* __restrict__ Dh,
                                                       unsigned short* __restrict__ Dl, int p) {
  extern __shared__ float sh[];
  int b = blockIdx.x, t = threadIdx.x;
  panel_factor_1024(sh, A + (size_t)b * kN * kN, Dg + (size_t)(b * 8 + p) * 16384,
                    Dh + (size_t)(b * 8 + p) * 16384, Dl + (size_t)(b * 8 + p) * 16384,
                    p * 128, t, false);
}

// ---------------- L21 = A21 * D_p^T (in place) + bf16(RN) of -L ----------------
__global__ __launch_bounds__(256) void chol_trsm(float* __restrict__ A,
                                                 const float* __restrict__ Dg,
                                                 unsigned short* __restrict__ Lh, int p) {
  __shared__ float At[128 * 129];
  __shared__ float Dt[128 * 129];
  int b = blockIdx.y, rb = blockIdx.x;
  int rs = (p + 1 + rb) * 128;
  float* Ab = A + (size_t)b * kN * kN;
  const float* Db = Dg + (size_t)(b * 8 + p) * 16384;
  int t = threadIdx.x;
  for (int q = 0; q < 64; ++q) {
    int li = t + 256 * q;
    int r = li >> 7, cc = li & 127;
    At[r * 129 + cc] = Ab[(size_t)(rs + r) * kN + p * 128 + cc];
    Dt[r * 129 + cc] = Db[r * 128 + cc];
  }
  __syncthreads();
  int tx = t & 15, ty = t >> 4;
  float acc[8][8] = {};
  for (int j = 0; j < 128; ++j) {
    float a[8], d[8];
#pragma unroll
    for (int q = 0; q < 8; ++q) a[q] = At[(ty * 8 + q) * 129 + j];
#pragma unroll
    for (int q = 0; q < 8; ++q) d[q] = Dt[(tx * 8 + q) * 129 + j];
#pragma unroll
    for (int qr = 0; qr < 8; ++qr)
#pragma unroll
      for (int qc = 0; qc < 8; ++qc) acc[qr][qc] = fmaf(a[qr], d[qc], acc[qr][qc]);
  }
#pragma unroll
  for (int qr = 0; qr < 8; ++qr)
#pragma unroll
    for (int qc = 0; qc < 8; ++qc) {
      float v = acc[qr][qc];
      Ab[(size_t)(rs + ty * 8 + qr) * kN + p * 128 + tx * 8 + qc] = v;
      size_t lo = ((size_t)b * kN + rs + ty * 8 + qr) * kN + p * 128 + tx * 8 + qc;
      Lh[lo] = b16rn(-v);
    }
}

// ---------------- fused syrk (1024 thr, 4x4 tiles) + lookahead panel(p+1) on pid==0 ----
__global__ __launch_bounds__(1024, 1) void chol_syrk_panel(float* __restrict__ A,
                                                           float* __restrict__ Dg,
                                                           unsigned short* __restrict__ Dh,
                                                           unsigned short* __restrict__ Dl,
                                                           int p) {
  extern __shared__ float sh[];
  float* L1t = sh + SYR_L1;
  float* L2t = sh + SYR_L2;
  int b = blockIdx.y;
  int pid = blockIdx.x;
  int bi = 0;
  while ((bi + 1) * (bi + 2) / 2 <= pid) ++bi;
  int bj = pid - bi * (bi + 1) / 2;
  int rs1 = (p + 1 + bi) * 128, rs2 = (p + 1 + bj) * 128;
  float* Ab = A + (size_t)b * kN * kN;
  int t = threadIdx.x;
#pragma unroll
  for (int q = 0; q < 16; ++q) {
    int li = t + 1024 * q;
    int r = li >> 7, cc = li & 127;
    L1t[r * 129 + cc] = Ab[(size_t)(rs1 + r) * kN + p * 128 + cc];
    L2t[r * 129 + cc] = Ab[(size_t)(rs2 + r) * kN + p * 128 + cc];
  }
  __syncthreads();
  int tx = t & 31, ty = t >> 5;  // 32x32 grid of 4x4 tiles
  float acc[4][4] = {};
  for (int j = 0; j < 128; ++j) {
    float a[4], d[4];
#pragma unroll
    for (int q = 0; q < 4; ++q) a[q] = L1t[(ty * 4 + q) * 129 + j];
#pragma unroll
    for (int q = 0; q < 4; ++q) d[q] = L2t[(tx * 4 + q) * 129 + j];
#pragma unroll
    for (int qr = 0; qr < 4; ++qr)
#pragma unroll
      for (int qc = 0; qc < 4; ++qc) acc[qr][qc] = fmaf(a[qr], d[qc], acc[qr][qc]);
  }
  if (pid != 0) {
#pragma unroll
    for (int qr = 0; qr < 4; ++qr)
#pragma unroll
      for (int qc = 0; qc < 4; ++qc) {
        size_t o = (size_t)(rs1 + ty * 4 + qr) * kN + rs2 + tx * 4 + qc;
        Ab[o] -= acc[qr][qc];
      }
    return;
  }
  // pid==0: diag pair (p+1,p+1). Build updated block in panel LDS, factor in-launch.
  __syncthreads();  // all GEMM reads of L1t/L2t done before At overwrite
  float* At = sh + PAN_AT;
#pragma unroll
  for (int qr = 0; qr < 4; ++qr)
#pragma unroll
    for (int qc = 0; qc < 4; ++qc) {
      float ao = Ab[(size_t)(rs1 + ty * 4 + qr) * kN + rs2 + tx * 4 + qc];
      At[(ty * 4 + qr) * 132 + tx * 4 + qc] = ao - acc[qr][qc];
    }
  int pn = p + 1;
  panel_factor_1024(sh, Ab, Dg + (size_t)(b * 8 + pn) * 16384,
                    Dh + (size_t)(b * 8 + pn) * 16384, Dl + (size_t)(b * 8 + pn) * 16384,
                    pn * 128, t, true);
}

// ---------------- z = L^-1 (y - mean), nlml (1024 thr, LDS-staged) ----------------
__global__ __launch_bounds__(1024) void solve_small(
    const float* __restrict__ A, const float* __restrict__ Dg,
    const float* __restrict__ y, const float* __restrict__ meanp,
    float* __restrict__ zbuf, float* __restrict__ out) {
  __shared__ float Ls[128 * 132];
  __shared__ __align__(16) float zs[1024];
  __shared__ float ts[128];
  __shared__ float part[128 * 9];
  __shared__ float red[1024];
  int b = blockIdx.x, t = threadIdx.x;
  int row = t & 127, g = t >> 7;
  const float* Ab = A + (size_t)b * kN * kN;
  float mv = meanp[b];
  zs[t] = y[b * kN + t] - mv;
  __syncthreads();
  for (int i = 0; i < 8; ++i) {
    float ps = 0.0f;
    for (int k = 0; k < i; ++k) {
#pragma unroll
      for (int q = 0; q < 4; ++q) {
        int li = t + 1024 * q;
        int r = li >> 5, c4 = li & 31;
        *(float4*)&Ls[r * 132 + c4 * 4] =
            *(const float4*)&Ab[(size_t)(i * 128 + r) * kN + k * 128 + c4 * 4];
      }
      __syncthreads();
      const float* Lr = &Ls[row * 132 + g * 16];
      const float* zk = &zs[k * 128 + g * 16];
#pragma unroll
      for (int c = 0; c < 16; c += 4) {
        float4 lv = *(const float4*)&Lr[c];
        float4 zv = *(const float4*)&zk[c];
        ps += lv.x * zv.x + lv.y * zv.y + lv.z * zv.z + lv.w * zv.w;
      }
      __syncthreads();
    }
    part[row * 9 + g] = ps;
    {
      const float* Db = Dg + (size_t)(b * 8 + i) * 16384;
#pragma unroll
      for (int q = 0; q < 4; ++q) {
        int li = t + 1024 * q;
        int r = li >> 5, c4 = li & 31;
        *(float4*)&Ls[r * 132 + c4 * 4] = *(const float4*)&Db[r * 128 + c4 * 4];
      }
    }
    __syncthreads();
    if (g == 0) {
      float acc = zs[i * 128 + row];
#pragma unroll
      for (int gg = 0; gg < 8; ++gg) acc -= part[row * 9 + gg];
      ts[row] = acc;
    }
    __syncthreads();
    float s = 0.0f;
    int c0 = g * 16, c1 = min(c0 + 16, row + 1);
    for (int c = c0; c < c1; ++c) s += Ls[row * 132 + c] * ts[c];
    part[row * 9 + g] = s;
    __syncthreads();
    if (g == 0) {
      float zv = 0.0f;
#pragma unroll
      for (int gg = 0; gg < 8; ++gg) zv += part[row * 9 + gg];
      zs[i * 128 + row] = zv;
    }
    __syncthreads();
  }
  red[t] = zs[t] * zs[t];
  __syncthreads();
  for (int s = 512; s > 0; s >>= 1) {
    if (t < s) red[t] += red[t + s];
    __syncthreads();
  }
  float dfs = red[0];
  __syncthreads();
  red[t] = logf(Ab[(size_t)t * kN + t]);
  __syncthreads();
  for (int s = 512; s > 0; s >>= 1) {
    if (t < s) red[t] += red[t + s];
    __syncthreads();
  }
  if (t == 0)
    out[2 * kB * kM + b] = 0.5f * dfs + red[0] + 0.5f * 1024.0f * logf(6.283185307179586f);
  zbuf[b * kN + t] = zs[t];
}

// ---------------- fused MFMA solve: K build + w = L^-1 K + outputs ----------------
__global__ __launch_bounds__(256, 2) void fused_mfma(
    const unsigned short* __restrict__ Lh,
    const unsigned short* __restrict__ Dh, const unsigned short* __restrict__ Dl,
    const float* __restrict__ xt, const float* __restrict__ pt,
    const float* __restrict__ xs, const float* __restrict__ ps,
    const float* __restrict__ sp, const float* __restrict__ meanp,
    const float* __restrict__ zbuf, float* __restrict__ out) {
  __shared__ unsigned short Th[32 * 136];
  __shared__ unsigned short Tl[32 * 136];
  __shared__ float trp[128 * 6];
  __shared__ float tp[32 * 6];
  __shared__ float zs[128];
  __shared__ float red[32 * 16 * 2];
  int bid = blockIdx.x;
  int xcd = bid & 7;
  int b = xcd >> 2;
  int mt = (xcd & 3) * 128 + (bid >> 3);
  int t = threadIdx.x;
  int lane = t & 63, wave = t >> 6;
  int lrow = lane & 15, kgrp = lane >> 4;
  float scale = __expf(sp[0]);
  if (t < 32) {
    int mg = mt * 32 + t;
    float x0 = xs[((size_t)b * kM + mg) * 2 + 0];
    float x1 = xs[((size_t)b * kM + mg) * 2 + 1];
    float a = ps[((size_t)b * kM + mg) * 3 + 0];
    float bb = ps[((size_t)b * kM + mg) * 3 + 1];
    float c = ps[((size_t)b * kM + mg) * 3 + 2];
    float det2 = a * bb - c * c;
    tp[t * 6 + 0] = x0; tp[t * 6 + 1] = x1; tp[t * 6 + 2] = a;
    tp[t * 6 + 3] = bb; tp[t * 6 + 4] = c; tp[t * 6 + 5] = sqrtf(sqrtf(det2));
  }
  floatx4 W[8][2][2];
#pragma unroll
  for (int i = 0; i < 8; ++i)
#pragma unroll
    for (int rf = 0; rf < 2; ++rf)
#pragma unroll
      for (int cf = 0; cf < 2; ++cf) W[i][rf][cf] = (floatx4){0.f, 0.f, 0.f, 0.f};
  float pma[2] = {0.f, 0.f}, s2a[2] = {0.f, 0.f};

#define FUSED_K_STEP(KC)                                                                   \
  {                                                                                        \
    constexpr int k = (KC);                                                                \
    __syncthreads();                                                                       \
    if (t < 128) {                                                                         \
      size_t n = (size_t)b * kN + k * 128 + t;                                             \
      float x0 = xt[n * 2 + 0];                                                            \
      float x1 = xt[n * 2 + 1];                                                            \
      float a = pt[n * 3 + 0];                                                             \
      float bb = pt[n * 3 + 1];                                                            \
      float c = pt[n * 3 + 2];                                                             \
      float det1 = a * bb - c * c;                                                         \
      trp[t * 6 + 0] = x0; trp[t * 6 + 1] = x1; trp[t * 6 + 2] = a;                        \
      trp[t * 6 + 3] = bb; trp[t * 6 + 4] = c;                                             \
      trp[t * 6 + 5] = 2.0f * scale * sqrtf(sqrtf(det1));                                  \
      zs[t] = zbuf[n];                                                                     \
    }                                                                                      \
    __syncthreads();                                                                       \
    _Pragma("unroll")                                                                      \
    for (int rf = 0; rf < 2; ++rf) {                                                       \
      int n0 = wave * 32 + rf * 16 + kgrp * 4;                                             \
      float nx0[4], nx1[4], na[4], nb[4], nc[4], nc1[4];                                   \
      _Pragma("unroll")                                                                    \
      for (int r = 0; r < 4; ++r) {                                                        \
        int n = n0 + r;                                                                    \
        nx0[r] = trp[n * 6 + 0]; nx1[r] = trp[n * 6 + 1]; na[r] = trp[n * 6 + 2];          \
        nb[r] = trp[n * 6 + 3]; nc[r] = trp[n * 6 + 4]; nc1[r] = trp[n * 6 + 5];           \
      }                                                                                    \
      _Pragma("unroll")                                                                    \
      for (int cf = 0; cf < 2; ++cf) {                                                     \
        int m = cf * 16 + lrow;                                                            \
        float mx0 = tp[m * 6 + 0], mx1 = tp[m * 6 + 1], ma = tp[m * 6 + 2];                \
        float mb = tp[m * 6 + 3], mc = tp[m * 6 + 4], mq = tp[m * 6 + 5];                  \
        float Tv[4];                                                                       \
        _Pragma("unroll")                                                                  \
        for (int r = 0; r < 4; ++r) {                                                      \
          float s00 = na[r] + ma, s11 = nb[r] + mb, s01 = nc[r] + mc;                      \
          float sdet = s00 * s11 - s01 * s01;                                              \
          float d0 = nx0[r] - mx0, d1 = nx1[r] - mx1;                                      \
          float quad = s11 * d0 * d0 - 2.0f * s01 * d0 * d1 + s00 * d1 * d1;               \
          float Q = __fdividef(0.5f * quad, sdet);                                         \
          float x3 = 3.0f * fmaxf(Q, 1e-5f);                                               \
          float tt = x3 * rsqrtf(x3);                                                      \
          float Kv = (1.0f + tt) * __expf(-tt) * nc1[r] * (mq * rsqrtf(fmaxf(sdet, 1e-5f))); \
          Tv[r] = Kv + W[k][rf][cf][r];                                                    \
        }                                                                                  \
        unsigned hw[2], lw[2];                                                             \
        pack2(Tv[0], Tv[1], hw[0], lw[0]);                                                 \
        pack2(Tv[2], Tv[3], hw[1], lw[1]);                                                 \
        int off = m * 136 + n0;                                                            \
        *(uint2*)&Th[off] = make_uint2(hw[0], hw[1]);                                      \
        *(uint2*)&Tl[off] = make_uint2(lw[0], lw[1]);                                      \
      }                                                                                    \
    }                                                                                      \
    __syncthreads();                                                                       \
    floatx4 wk[2][2];                                                                      \
    _Pragma("unroll")                                                                      \
    for (int rf = 0; rf < 2; ++rf)                                                         \
      _Pragma("unroll")                                                                    \
      for (int cf = 0; cf < 2; ++cf) wk[rf][cf] = (floatx4){0.f, 0.f, 0.f, 0.f};           \
    {                                                                                      \
      const unsigned short* Dhb = Dh + (size_t)(b * 8 + k) * 16384;                        \
      const unsigned short* Dlb = Dl + (size_t)(b * 8 + k) * 16384;                        \
      _Pragma("unroll")                                                                    \
      for (int ks = 0; ks < 4; ++ks) {                                                     \
        short8v bh[2], bl[2];                                                              \
        _Pragma("unroll")                                                                  \
        for (int cf = 0; cf < 2; ++cf) {                                                   \
          int boff = (cf * 16 + lrow) * 136 + ks * 32 + kgrp * 8;                          \
          bh[cf] = *(const short8v*)&Th[boff];                                             \
          bl[cf] = *(const short8v*)&Tl[boff];                                             \
        }                                                                                  \
        short8v ah[2], al[2];                                                              \
        _Pragma("unroll")                                                                  \
        for (int rf = 0; rf < 2; ++rf) {                                                   \
          size_t aoff = (size_t)(wave * 32 + rf * 16 + lrow) * 128 + ks * 32 + kgrp * 8;   \
          ah[rf] = *(const short8v*)&Dhb[aoff];                                            \
          al[rf] = *(const short8v*)&Dlb[aoff];                                            \
        }                                                                                  \
        _Pragma("unroll")                                                                  \
        for (int rf = 0; rf < 2; ++rf)                                                     \
          _Pragma("unroll")                                                                \
          for (int cf = 0; cf < 2; ++cf) {                                                 \
            wk[rf][cf] = __builtin_amdgcn_mfma_f32_16x16x32_bf16(ah[rf], bh[cf], wk[rf][cf], 0, 0, 0); \
            wk[rf][cf] = __builtin_amdgcn_mfma_f32_16x16x32_bf16(ah[rf], bl[cf], wk[rf][cf], 0, 0, 0); \
            wk[rf][cf] = __builtin_amdgcn_mfma_f32_16x16x32_bf16(al[rf], bh[cf], wk[rf][cf], 0, 0, 0); \
          }                                                                                \
      }                                                                                    \
    }                                                                                      \
    __syncthreads();                                                                       \
    _Pragma("unroll")                                                                      \
    for (int rf = 0; rf < 2; ++rf) {                                                       \
      int n0 = wave * 32 + rf * 16 + kgrp * 4;                                             \
      _Pragma("unroll")                                                                    \
      for (int cf = 0; cf < 2; ++cf) {                                                     \
        int m = cf * 16 + lrow;                                                            \
        float wv[4];                                                                       \
        _Pragma("unroll")                                                                  \
        for (int r = 0; r < 4; ++r) {                                                      \
          wv[r] = wk[rf][cf][r];                                                           \
          pma[cf] = fmaf(wv[r], zs[n0 + r], pma[cf]);                                      \
          s2a[cf] = fmaf(wv[r], wv[r], s2a[cf]);                                           \
        }                                                                                  \
        unsigned hw[2], lw[2];                                                             \
        pack2(wv[0], wv[1], hw[0], lw[0]);                                                 \
        pack2(wv[2], wv[3], hw[1], lw[1]);                                                 \
        int off = m * 136 + n0;                                                            \
        *(uint2*)&Th[off] = make_uint2(hw[0], hw[1]);                                      \
        *(uint2*)&Tl[off] = make_uint2(lw[0], lw[1]);                                      \
      }                                                                                    \
    }                                                                                      \
    __syncthreads();                                                                       \
    __builtin_amdgcn_s_setprio(1);                                                         \
    _Pragma("unroll")                                                                      \
    for (int ks = 0; ks < 4; ++ks) {                                                       \
      short8v bh[2], bl[2];                                                                \
      _Pragma("unroll")                                                                    \
      for (int cf = 0; cf < 2; ++cf) {                                                     \
        int boff = (cf * 16 + lrow) * 136 + ks * 32 + kgrp * 8;                            \
        bh[cf] = *(const short8v*)&Th[boff];                                               \
        bl[cf] = *(const short8v*)&Tl[boff];                                               \
      }                                                                                    \
      _Pragma("unroll")                                                                    \
      for (int i = k + 1; i < 8; ++i) {                                                    \
        short8v ah[2];                                                                     \
        _Pragma("unroll")                                                                  \
        for (int rf = 0; rf < 2; ++rf) {                                                   \
          size_t ro = (size_t)b * kN + i * 128 + wave * 32 + rf * 16 + lrow;               \
          size_t aoff = ro * kN + k * 128 + ks * 32 + kgrp * 8;                            \
          ah[rf] = *(const short8v*)&Lh[aoff];                                             \
        }                                                                                  \
        _Pragma("unroll")                                                                  \
        for (int rf = 0; rf < 2; ++rf)                                                     \
          _Pragma("unroll")                                                                \
          for (int cf = 0; cf < 2; ++cf) {                                                 \
            W[i][rf][cf] = __builtin_amdgcn_mfma_f32_16x16x32_bf16(ah[rf], bh[cf], W[i][rf][cf], 0, 0, 0); \
            W[i][rf][cf] = __builtin_amdgcn_mfma_f32_16x16x32_bf16(ah[rf], bl[cf], W[i][rf][cf], 0, 0, 0); \
          }                                                                                \
      }                                                                                    \
    }                                                                                      \
    __builtin_amdgcn_s_setprio(0);                                                         \
  }

  FUSED_K_STEP(0)
  FUSED_K_STEP(1)
  FUSED_K_STEP(2)
  FUSED_K_STEP(3)
  FUSED_K_STEP(4)
  FUSED_K_STEP(5)
  FUSED_K_STEP(6)
  FUSED_K_STEP(7)
#undef FUSED_K_STEP

  __syncthreads();
#pragma unroll
  for (int cf = 0; cf < 2; ++cf) {
    int m = cf * 16 + lrow;
    red[m * 16 + wave * 4 + kgrp] = pma[cf];
    red[512 + m * 16 + wave * 4 + kgrp] = s2a[cf];
  }
  __syncthreads();
  if (t < 32) {
    float pm = 0.f, s2 = 0.f;
#pragma unroll
    for (int j = 0; j < 16; ++j) {
      pm += red[t * 16 + j];
      s2 += red[512 + t * 16 + j];
    }
    int mg = mt * 32 + t;
    float a = tp[t * 6 + 2], bb = tp[t * 6 + 3], c = tp[t * 6 + 4];
    float det = a * bb - c * c;
    float C = 2.0f * sqrtf(det) * rsqrtf(fmaxf(4.0f * det, 1e-5f));
    float t0 = kSqrt3 * sqrtf(1e-5f);
    float mat = (1.0f + t0) * __expf(-t0);
    float kd = C * mat * scale;
    out[b * kM + mg] = meanp[b] + pm;
    out[kB * kM + b * kM + mg] = kd - s2;
  }
}

extern "C" void kernel_launch(void* const* d_in, const int* in_sizes, int n_in,
                              void* d_out, int out_size, void* d_ws, size_t ws_size,
                              hipStream_t stream) {
  const float* xt = (const float*)d_in[0];
  const float* pt = (const float*)d_in[1];
  const float* xs = (const float*)d_in[2];
  const float* ps = (const float*)d_in[3];
  const float* y = (const float*)d_in[4];
  const float* var = (const float*)d_in[5];
  const float* meanp = (const float*)d_in[6];
  const float* sp = (const float*)d_in[7];
  float* out = (float*)d_out;
  char* ws = (char*)d_ws;
  if (ws_size < WS_BYTES) return;

  float* A = (float*)(ws + A_OFF);
  float* Dg = (float*)(ws + DG_OFF);
  float* zbuf = (float*)(ws + Z_OFF);
  unsigned short* Lh = (unsigned short*)(ws + LH_OFF);
  unsigned short* Dh = (unsigned short*)(ws + DH_OFF);
  unsigned short* Dl = (unsigned short*)(ws + DL_OFF);

  const size_t panLds = PAN_FLOATS * sizeof(float);  // 147840 B

  build_A<<<(kB * kN * kN) / 256, 256, 0, stream>>>(xt, pt, var, sp, A);
  chol_panel0<<<kB, 1024, panLds, stream>>>(A, Dg, Dh, Dl, 0);
  for (int p = 0; p < 7; ++p) {
    int nt = 7 - p;
    chol_trsm<<<dim3(nt, kB), 256, 0, stream>>>(A, Dg, Lh, p);
    int npairs = nt * (nt + 1) / 2;
    chol_syrk_panel<<<dim3(npairs, kB), 1024, panLds, stream>>>(A, Dg, Dh, Dl, p);
  }
  solve_small<<<kB, 1024, 0, stream>>>(A, Dg, y, meanp, zbuf, out);
  fused_mfma<<<kB * 512, 256, 0, stream>>>(Lh, Dh, Dl, xt, pt, xs, ps,
                                           sp, meanp, zbuf, out);
}

// Round 11
// 1133.648 us; speedup vs baseline: 1.1953x; 1.0967x over previous
//
#include <hip/hip_runtime.h>
#include <math.h>

namespace {
constexpr int kB = 2;
constexpr int kN = 1024;
constexpr int kM = 16384;
constexpr float kSqrt3 = 1.7320508075688772f;

// workspace layout (bytes)
constexpr size_t A_BYTES = (size_t)kB * kN * kN * 4;
constexpr size_t DG_BYTES = (size_t)kB * 8 * 128 * 128 * 4;
constexpr size_t Z_BYTES = (size_t)kB * kN * 4;
constexpr size_t LH_BYTES = (size_t)kB * kN * kN * 2;
constexpr size_t DH_BYTES = (size_t)kB * 8 * 128 * 128 * 2;
constexpr size_t A_OFF = 0;
constexpr size_t DG_OFF = A_OFF + A_BYTES;
constexpr size_t Z_OFF = DG_OFF + DG_BYTES;
constexpr size_t LH_OFF = Z_OFF + Z_BYTES;
constexpr size_t LL_OFF = LH_OFF + LH_BYTES;   // (unused)
constexpr size_t DH_OFF = LL_OFF + LH_BYTES;
constexpr size_t DL_OFF = DH_OFF + DH_BYTES;
constexpr size_t WS_BYTES = DL_OFF + DH_BYTES;
}  // namespace

typedef __attribute__((ext_vector_type(8))) short short8v;
typedef __attribute__((ext_vector_type(4))) float floatx4;

__device__ __forceinline__ float b16f(unsigned short h) {
  return __uint_as_float(((unsigned)h) << 16);
}
__device__ __forceinline__ unsigned short b16rn(float x) {
  unsigned u = __float_as_uint(x);
  unsigned r = u + 0x7FFFu + ((u >> 16) & 1u);
  return (unsigned short)(r >> 16);
}
__device__ __forceinline__ void split_bf16(float x, unsigned short& h, unsigned short& l) {
  unsigned u = __float_as_uint(x);
  h = (unsigned short)(u >> 16);
  float rem = x - b16f(h);
  l = (unsigned short)(__float_as_uint(rem) >> 16);
}
__device__ __forceinline__ void pack2(float v0, float v1, unsigned& hw, unsigned& lw) {
  unsigned u0 = __float_as_uint(v0), u1 = __float_as_uint(v1);
  unsigned h0 = u0 & 0xFFFF0000u;
  unsigned h1 = u1 & 0xFFFF0000u;
  hw = (h0 >> 16) | h1;
  float r0 = v0 - __uint_as_float(h0);
  float r1 = v1 - __uint_as_float(h1);
  lw = (__float_as_uint(r0) >> 16) | (__float_as_uint(r1) & 0xFFFF0000u);
}

// cheap pair math: one rsqrt shared between Q and C; u = 3Q via rsq^2.
__device__ __forceinline__ float pair_kernel(
    float x0, float x1, float a1, float b1, float c1,
    float y0, float y1, float a2, float b2, float c2, float scale) {
  float det1 = a1 * b1 - c1 * c1;
  float det2 = a2 * b2 - c2 * c2;
  float s00 = a1 + a2, s11 = b1 + b2, s01 = c1 + c2;
  float sdet = s00 * s11 - s01 * s01;
  float rsq = rsqrtf(fmaxf(sdet, 1e-5f));
  float d0 = x0 - y0, d1 = x1 - y1;
  float quad = s11 * d0 * d0 - 2.0f * s01 * d0 * d1 + s00 * d1 * d1;
  float u = 1.5f * quad * rsq * rsq;            // = 3*Q
  float t = sqrtf(fmaxf(u, 3e-5f));             // = sqrt(3*max(Q,1e-5))
  float C = 2.0f * sqrtf(sqrtf(det1)) * sqrtf(sqrtf(det2)) * rsq;
  return (1.0f + t) * __expf(-t) * C * scale;
}

// ---------------- A = K_nn + diag(var) ----------------
__global__ __launch_bounds__(256) void build_A(
    const float* __restrict__ xt, const float* __restrict__ pt,
    const float* __restrict__ var, const float* __restrict__ sp,
    float* __restrict__ A) {
  int idx = blockIdx.x * 256 + threadIdx.x;
  int b = idx / (kN * kN);
  int r = (idx / kN) % kN;
  int c = idx % kN;
  float scale = __expf(sp[0]);
  const float* x1 = xt + ((size_t)b * kN + r) * 2;
  const float* p1 = pt + ((size_t)b * kN + r) * 3;
  const float* x2 = xt + ((size_t)b * kN + c) * 2;
  const float* p2 = pt + ((size_t)b * kN + c) * 3;
  float k = pair_kernel(x1[0], x1[1], p1[0], p1[1], p1[2],
                        x2[0], x2[1], p2[0], p2[1], p2[2], scale);
  if (r == c) k += var[b * kN + r];
  A[(size_t)idx] = k;
}

__device__ __forceinline__ void tri_decode(int idx, int& ti, int& tj) {
  float f = sqrtf(8.0f * (float)idx + 1.0f);
  int t0 = (int)((f - 1.0f) * 0.5f);
  while (t0 * (t0 + 1) / 2 > idx) --t0;
  while ((t0 + 1) * (t0 + 2) / 2 <= idx) ++t0;
  ti = t0;
  tj = idx - t0 * (t0 + 1) / 2;
}

// ---------------- Cholesky panel: pipelined rank-8 lookahead, 1024 thr (R8) -----------
__global__ __launch_bounds__(1024, 1) void chol_panel(float* __restrict__ A,
                                                      float* __restrict__ Dg,
                                                      unsigned short* __restrict__ Dh,
                                                      unsigned short* __restrict__ Dl, int p) {
  __shared__ float At[128 * 132];
  __shared__ float Dt[128 * 132];
  __shared__ float Tt[3 * 32 * 33];
  int b = blockIdx.x, t = threadIdx.x;
  float* Ab = A + (size_t)b * kN * kN;
  int r0 = p * 128;
#pragma unroll
  for (int q = 0; q < 4; ++q) {
    int idx = t + 1024 * q;
    int r = idx >> 5, c4 = idx & 31;
    *(float4*)&At[r * 132 + c4 * 4] = *(const float4*)&Ab[(size_t)(r0 + r) * kN + r0 + c4 * 4];
  }
  __syncthreads();
  int wave = t >> 6, lane = t & 63;
  int row0 = lane, row1 = lane + 64;
  for (int kb = 0; kb < 16; ++kb) {
    int K0 = kb * 8;
    int Kp = K0 - 8;
    if (kb > 0) {
      if (wave == 0) {
        int rr = lane >> 3, cc = lane & 7;
        float s = 0.0f;
#pragma unroll
        for (int e = 0; e < 8; ++e)
          s += At[(K0 + rr) * 132 + Kp + e] * At[(K0 + cc) * 132 + Kp + e];
        At[(K0 + rr) * 132 + K0 + cc] -= s;
      } else {
        int n = 120 - 8 * kb;
        int nt = n >> 2;
        int ntt = nt * (nt + 1) / 2;
        int base = K0 + 8;
        for (int idx = t - 64; idx < ntt; idx += 960) {
          int ti, tj;
          tri_decode(idx, ti, tj);
          int i0 = base + ti * 4, j0 = base + tj * 4;
          float Li[4][8], Lj[4][8];
#pragma unroll
          for (int r = 0; r < 4; ++r) {
            *(float4*)&Li[r][0] = *(const float4*)&At[(i0 + r) * 132 + Kp];
            *(float4*)&Li[r][4] = *(const float4*)&At[(i0 + r) * 132 + Kp + 4];
            *(float4*)&Lj[r][0] = *(const float4*)&At[(j0 + r) * 132 + Kp];
            *(float4*)&Lj[r][4] = *(const float4*)&At[(j0 + r) * 132 + Kp + 4];
          }
#pragma unroll
          for (int r = 0; r < 4; ++r) {
            float4 cv = *(const float4*)&At[(i0 + r) * 132 + j0];
            float cc4[4] = {cv.x, cv.y, cv.z, cv.w};
#pragma unroll
            for (int c = 0; c < 4; ++c) {
              float s = 0.0f;
#pragma unroll
              for (int e = 0; e < 8; ++e) s += Li[r][e] * Lj[c][e];
              cc4[c] -= s;
            }
            float4 ov = {cc4[0], cc4[1], cc4[2], cc4[3]};
            *(float4*)&At[(i0 + r) * 132 + j0] = ov;
          }
        }
      }
    }
    __syncthreads();
    if (wave == 0) {
      float rA0[8], rA1[8];
      *(float4*)&rA0[0] = *(const float4*)&At[row0 * 132 + K0];
      *(float4*)&rA0[4] = *(const float4*)&At[row0 * 132 + K0 + 4];
      *(float4*)&rA1[0] = *(const float4*)&At[row1 * 132 + K0];
      *(float4*)&rA1[4] = *(const float4*)&At[row1 * 132 + K0 + 4];
      if (kb > 0) {
        float pA0[8], pA1[8];
        *(float4*)&pA0[0] = *(const float4*)&At[row0 * 132 + Kp];
        *(float4*)&pA0[4] = *(const float4*)&At[row0 * 132 + Kp + 4];
        *(float4*)&pA1[0] = *(const float4*)&At[row1 * 132 + Kp];
        *(float4*)&pA1[4] = *(const float4*)&At[row1 * 132 + Kp + 4];
#pragma unroll
        for (int j = 0; j < 8; ++j) {
          float s0 = 0.0f, s1 = 0.0f;
#pragma unroll
          for (int e = 0; e < 8; ++e) {
            float pj = At[(K0 + j) * 132 + Kp + e];
            s0 += pA0[e] * pj;
            s1 += pA1[e] * pj;
          }
          rA0[j] -= s0;
          rA1[j] -= s1;
        }
      }
      float L11[8][8], idg[8];
#pragma unroll
      for (int r = 0; r < 8; ++r) {
        *(float4*)&L11[r][0] = *(const float4*)&At[(K0 + r) * 132 + K0];
        *(float4*)&L11[r][4] = *(const float4*)&At[(K0 + r) * 132 + K0 + 4];
      }
#pragma unroll
      for (int c = 0; c < 8; ++c) {
        float d = sqrtf(L11[c][c]);
        float iv = 1.0f / d;
        idg[c] = iv;
        L11[c][c] = d;
#pragma unroll
        for (int i = c + 1; i < 8; ++i) L11[i][c] *= iv;
#pragma unroll
        for (int j = c + 1; j < 8; ++j)
#pragma unroll
          for (int i = j; i < 8; ++i) L11[i][j] -= L11[i][c] * L11[j][c];
      }
      if (row0 >= K0 + 8) {
#pragma unroll
        for (int c = 0; c < 8; ++c) {
          float s = rA0[c];
#pragma unroll
          for (int j = 0; j < c; ++j) s -= rA0[j] * L11[c][j];
          rA0[c] = s * idg[c];
        }
      } else if (row0 >= K0) {
#pragma unroll
        for (int rr = 0; rr < 8; ++rr)
          if (row0 - K0 == rr) {
#pragma unroll
            for (int e = 0; e < 8; ++e) rA0[e] = (e <= rr) ? L11[rr][e] : 0.0f;
          }
      }
      if (row1 >= K0 + 8) {
#pragma unroll
        for (int c = 0; c < 8; ++c) {
          float s = rA1[c];
#pragma unroll
          for (int j = 0; j < c; ++j) s -= rA1[j] * L11[c][j];
          rA1[c] = s * idg[c];
        }
      } else if (row1 >= K0) {
#pragma unroll
        for (int rr = 0; rr < 8; ++rr)
          if (row1 - K0 == rr) {
#pragma unroll
            for (int e = 0; e < 8; ++e) rA1[e] = (e <= rr) ? L11[rr][e] : 0.0f;
          }
      }
      if (row0 >= K0) {
        float4 v0 = {rA0[0], rA0[1], rA0[2], rA0[3]};
        float4 v1 = {rA0[4], rA0[5], rA0[6], rA0[7]};
        *(float4*)&At[row0 * 132 + K0] = v0;
        *(float4*)&At[row0 * 132 + K0 + 4] = v1;
      }
      if (row1 >= K0) {
        float4 v0 = {rA1[0], rA1[1], rA1[2], rA1[3]};
        float4 v1 = {rA1[4], rA1[5], rA1[6], rA1[7]};
        *(float4*)&At[row1 * 132 + K0] = v0;
        *(float4*)&At[row1 * 132 + K0 + 4] = v1;
      }
    }
    __syncthreads();
  }
  if (t < 128) {
    int q = t >> 5, c = t & 31, bse = q * 32;
    float x[32];
#pragma unroll
    for (int r = 0; r < 32; ++r) {
      float s = (r == c) ? 1.0f : 0.0f;
#pragma unroll
      for (int j = 0; j < 32; ++j)
        if (j < r) s -= At[(bse + r) * 132 + bse + j] * x[j];
      x[r] = (r < c) ? 0.0f : s / At[(bse + r) * 132 + bse + r];
    }
#pragma unroll
    for (int r = 0; r < 32; ++r) Dt[(bse + r) * 132 + bse + c] = x[r];
  }
  __syncthreads();
  {
    int r = t >> 5, cl = t & 31;
    for (int s = 1; s <= 3; ++s) {
      for (int blk = 0; blk < 4 - s; ++blk) {
        int J = blk, I = J + s;
        float sum = 0.0f;
        for (int K = J; K < I; ++K)
          for (int j = 0; j < 32; ++j)
            sum += At[(I * 32 + r) * 132 + K * 32 + j] * Dt[(K * 32 + j) * 132 + J * 32 + cl];
        Tt[blk * (32 * 33) + r * 33 + cl] = sum;
      }
      __syncthreads();
      for (int blk = 0; blk < 4 - s; ++blk) {
        int J = blk, I = J + s;
        float sum = 0.0f;
        for (int j = 0; j < 32; ++j)
          sum += Dt[(I * 32 + r) * 132 + I * 32 + j] * Tt[blk * (32 * 33) + j * 33 + cl];
        Dt[(I * 32 + r) * 132 + J * 32 + cl] = -sum;
      }
      __syncthreads();
    }
  }
#pragma unroll
  for (int q = 0; q < 4; ++q) {
    int jj = t + 1024 * q;
    int r = jj >> 5, ch = jj & 31;
    int c0 = ch * 4;
    float4 v = *(const float4*)&At[r * 132 + c0];
    v.x = (c0 + 0 <= r) ? v.x : 0.0f;
    v.y = (c0 + 1 <= r) ? v.y : 0.0f;
    v.z = (c0 + 2 <= r) ? v.z : 0.0f;
    v.w = (c0 + 3 <= r) ? v.w : 0.0f;
    *(float4*)&Ab[(size_t)(r0 + r) * kN + r0 + c0] = v;
  }
  float* Db = Dg + (size_t)(b * 8 + p) * 16384;
  unsigned short* Dhb = Dh + (size_t)(b * 8 + p) * 16384;
  unsigned short* Dlb = Dl + (size_t)(b * 8 + p) * 16384;
#pragma unroll
  for (int q = 0; q < 4; ++q) {
    int jj = t + 1024 * q;
    int r = jj >> 5, ch = jj & 31;
    int c0 = ch * 4;
    float4 v = *(const float4*)&Dt[r * 132 + c0];
    v.x = (c0 + 0 <= r) ? v.x : 0.0f;
    v.y = (c0 + 1 <= r) ? v.y : 0.0f;
    v.z = (c0 + 2 <= r) ? v.z : 0.0f;
    v.w = (c0 + 3 <= r) ? v.w : 0.0f;
    *(float4*)&Db[r * 128 + c0] = v;
    float vv[4] = {v.x, v.y, v.z, v.w};
    unsigned short hs[4], ls[4];
#pragma unroll
    for (int e = 0; e < 4; ++e) split_bf16(vv[e], hs[e], ls[e]);
    *(ushort4*)&Dhb[r * 128 + c0] = make_ushort4(hs[0], hs[1], hs[2], hs[3]);
    *(ushort4*)&Dlb[r * 128 + c0] = make_ushort4(ls[0], ls[1], ls[2], ls[3]);
  }
}

// ---------------- L21 = A21 * D_p^T (in place) + bf16(RN) of -L ----------------
__global__ __launch_bounds__(256) void chol_trsm(float* __restrict__ A,
                                                 const float* __restrict__ Dg,
                                                 unsigned short* __restrict__ Lh, int p) {
  __shared__ float At[128 * 129];
  __shared__ float Dt[128 * 129];
  int b = blockIdx.y, rb = blockIdx.x;
  int rs = (p + 1 + rb) * 128;
  float* Ab = A + (size_t)b * kN * kN;
  const float* Db = Dg + (size_t)(b * 8 + p) * 16384;
  int t = threadIdx.x;
  for (int q = 0; q < 64; ++q) {
    int li = t + 256 * q;
    int r = li >> 7, cc = li & 127;
    At[r * 129 + cc] = Ab[(size_t)(rs + r) * kN + p * 128 + cc];
    Dt[r * 129 + cc] = Db[r * 128 + cc];
  }
  __syncthreads();
  int tx = t & 15, ty = t >> 4;
  float acc[8][8] = {};
  for (int j = 0; j < 128; ++j) {
    float a[8], d[8];
#pragma unroll
    for (int q = 0; q < 8; ++q) a[q] = At[(ty * 8 + q) * 129 + j];
#pragma unroll
    for (int q = 0; q < 8; ++q) d[q] = Dt[(tx * 8 + q) * 129 + j];
#pragma unroll
    for (int qr = 0; qr < 8; ++qr)
#pragma unroll
      for (int qc = 0; qc < 8; ++qc) acc[qr][qc] = fmaf(a[qr], d[qc], acc[qr][qc]);
  }
#pragma unroll
  for (int qr = 0; qr < 8; ++qr)
#pragma unroll
    for (int qc = 0; qc < 8; ++qc) {
      float v = acc[qr][qc];
      Ab[(size_t)(rs + ty * 8 + qr) * kN + p * 128 + tx * 8 + qc] = v;
      size_t lo = ((size_t)b * kN + rs + ty * 8 + qr) * kN + p * 128 + tx * 8 + qc;
      Lh[lo] = b16rn(-v);
    }
}

// ---------------- A22 -= L21 * L21^T ----------------
__global__ __launch_bounds__(256) void chol_syrk(float* __restrict__ A, int p) {
  __shared__ float L1t[128 * 129];
  __shared__ float L2t[128 * 129];
  int b = blockIdx.y;
  int pid = blockIdx.x;
  int bi = 0;
  while ((bi + 1) * (bi + 2) / 2 <= pid) ++bi;
  int bj = pid - bi * (bi + 1) / 2;
  int rs1 = (p + 1 + bi) * 128, rs2 = (p + 1 + bj) * 128;
  float* Ab = A + (size_t)b * kN * kN;
  int t = threadIdx.x;
  for (int q = 0; q < 64; ++q) {
    int li = t + 256 * q;
    int r = li >> 7, cc = li & 127;
    L1t[r * 129 + cc] = Ab[(size_t)(rs1 + r) * kN + p * 128 + cc];
    L2t[r * 129 + cc] = Ab[(size_t)(rs2 + r) * kN + p * 128 + cc];
  }
  __syncthreads();
  int tx = t & 15, ty = t >> 4;
  float acc[8][8] = {};
  for (int j = 0; j < 128; ++j) {
    float a[8], d[8];
#pragma unroll
    for (int q = 0; q < 8; ++q) a[q] = L1t[(ty * 8 + q) * 129 + j];
#pragma unroll
    for (int q = 0; q < 8; ++q) d[q] = L2t[(tx * 8 + q) * 129 + j];
#pragma unroll
    for (int qr = 0; qr < 8; ++qr)
#pragma unroll
      for (int qc = 0; qc < 8; ++qc) acc[qr][qc] = fmaf(a[qr], d[qc], acc[qr][qc]);
  }
#pragma unroll
  for (int qr = 0; qr < 8; ++qr)
#pragma unroll
    for (int qc = 0; qc < 8; ++qc) {
      size_t o = (size_t)(rs1 + ty * 8 + qr) * kN + rs2 + tx * 8 + qc;
      Ab[o] -= acc[qr][qc];
    }
}

// ---------------- z = L^-1 (y - mean), nlml (1024 thr, LDS-staged) ----------------
__global__ __launch_bounds__(1024) void solve_small(
    const float* __restrict__ A, const float* __restrict__ Dg,
    const float* __restrict__ y, const float* __restrict__ meanp,
    float* __restrict__ zbuf, float* __restrict__ out) {
  __shared__ float Ls[128 * 132];
  __shared__ __align__(16) float zs[1024];
  __shared__ float ts[128];
  __shared__ float part[128 * 9];
  __shared__ float red[1024];
  int b = blockIdx.x, t = threadIdx.x;
  int row = t & 127, g = t >> 7;
  const float* Ab = A + (size_t)b * kN * kN;
  float mv = meanp[b];
  zs[t] = y[b * kN + t] - mv;
  __syncthreads();
  for (int i = 0; i < 8; ++i) {
    float ps = 0.0f;
    for (int k = 0; k < i; ++k) {
#pragma unroll
      for (int q = 0; q < 4; ++q) {
        int li = t + 1024 * q;
        int r = li >> 5, c4 = li & 31;
        *(float4*)&Ls[r * 132 + c4 * 4] =
            *(const float4*)&Ab[(size_t)(i * 128 + r) * kN + k * 128 + c4 * 4];
      }
      __syncthreads();
      const float* Lr = &Ls[row * 132 + g * 16];
      const float* zk = &zs[k * 128 + g * 16];
#pragma unroll
      for (int c = 0; c < 16; c += 4) {
        float4 lv = *(const float4*)&Lr[c];
        float4 zv = *(const float4*)&zk[c];
        ps += lv.x * zv.x + lv.y * zv.y + lv.z * zv.z + lv.w * zv.w;
      }
      __syncthreads();
    }
    part[row * 9 + g] = ps;
    {
      const float* Db = Dg + (size_t)(b * 8 + i) * 16384;
#pragma unroll
      for (int q = 0; q < 4; ++q) {
        int li = t + 1024 * q;
        int r = li >> 5, c4 = li & 31;
        *(float4*)&Ls[r * 132 + c4 * 4] = *(const float4*)&Db[r * 128 + c4 * 4];
      }
    }
    __syncthreads();
    if (g == 0) {
      float acc = zs[i * 128 + row];
#pragma unroll
      for (int gg = 0; gg < 8; ++gg) acc -= part[row * 9 + gg];
      ts[row] = acc;
    }
    __syncthreads();
    float s = 0.0f;
    int c0 = g * 16, c1 = min(c0 + 16, row + 1);
    for (int c = c0; c < c1; ++c) s += Ls[row * 132 + c] * ts[c];
    part[row * 9 + g] = s;
    __syncthreads();
    if (g == 0) {
      float zv = 0.0f;
#pragma unroll
      for (int gg = 0; gg < 8; ++gg) zv += part[row * 9 + gg];
      zs[i * 128 + row] = zv;
    }
    __syncthreads();
  }
  red[t] = zs[t] * zs[t];
  __syncthreads();
  for (int s = 512; s > 0; s >>= 1) {
    if (t < s) red[t] += red[t + s];
    __syncthreads();
  }
  float dfs = red[0];
  __syncthreads();
  red[t] = logf(Ab[(size_t)t * kN + t]);
  __syncthreads();
  for (int s = 512; s > 0; s >>= 1) {
    if (t < s) red[t] += red[t + s];
    __syncthreads();
  }
  if (t == 0)
    out[2 * kB * kM + b] = 0.5f * dfs + red[0] + 0.5f * 1024.0f * logf(6.283185307179586f);
  zbuf[b * kN + t] = zs[t];
}

// ---------------- fused MFMA solve: K build + w = L^-1 K + outputs ----------------
// Double-buffered trp/zs (prefetch k+1 during wk MFMA): 4 barriers per k-step.
__global__ __launch_bounds__(256, 2) void fused_mfma(
    const unsigned short* __restrict__ Lh,
    const unsigned short* __restrict__ Dh, const unsigned short* __restrict__ Dl,
    const float* __restrict__ xt, const float* __restrict__ pt,
    const float* __restrict__ xs, const float* __restrict__ ps,
    const float* __restrict__ sp, const float* __restrict__ meanp,
    const float* __restrict__ zbuf, float* __restrict__ out) {
  __shared__ unsigned short Th[32 * 136];
  __shared__ unsigned short Tl[32 * 136];
  __shared__ float trp2[2][128 * 6];
  __shared__ float zs2[2][128];
  __shared__ float tp[32 * 6];
  __shared__ float red[32 * 16 * 2];
  int bid = blockIdx.x;
  int xcd = bid & 7;
  int b = xcd >> 2;
  int mt = (xcd & 3) * 128 + (bid >> 3);
  int t = threadIdx.x;
  int lane = t & 63, wave = t >> 6;
  int lrow = lane & 15, kgrp = lane >> 4;
  float scale = __expf(sp[0]);
  if (t < 32) {
    int mg = mt * 32 + t;
    float x0 = xs[((size_t)b * kM + mg) * 2 + 0];
    float x1 = xs[((size_t)b * kM + mg) * 2 + 1];
    float a = ps[((size_t)b * kM + mg) * 3 + 0];
    float bb = ps[((size_t)b * kM + mg) * 3 + 1];
    float c = ps[((size_t)b * kM + mg) * 3 + 2];
    float det2 = a * bb - c * c;
    tp[t * 6 + 0] = x0; tp[t * 6 + 1] = x1; tp[t * 6 + 2] = a;
    tp[t * 6 + 3] = bb; tp[t * 6 + 4] = c; tp[t * 6 + 5] = sqrtf(sqrtf(det2));
  }
  // prologue: load train rows for k=0
  if (t < 128) {
    size_t n = (size_t)b * kN + t;
    float x0 = xt[n * 2 + 0];
    float x1 = xt[n * 2 + 1];
    float a = pt[n * 3 + 0];
    float bb = pt[n * 3 + 1];
    float c = pt[n * 3 + 2];
    float det1 = a * bb - c * c;
    trp2[0][t * 6 + 0] = x0; trp2[0][t * 6 + 1] = x1; trp2[0][t * 6 + 2] = a;
    trp2[0][t * 6 + 3] = bb; trp2[0][t * 6 + 4] = c;
    trp2[0][t * 6 + 5] = 2.0f * scale * sqrtf(sqrtf(det1));
    zs2[0][t] = zbuf[n];
  }
  floatx4 W[8][2][2];
#pragma unroll
  for (int i = 0; i < 8; ++i)
#pragma unroll
    for (int rf = 0; rf < 2; ++rf)
#pragma unroll
      for (int cf = 0; cf < 2; ++cf) W[i][rf][cf] = (floatx4){0.f, 0.f, 0.f, 0.f};
  float pma[2] = {0.f, 0.f}, s2a[2] = {0.f, 0.f};
  __syncthreads();

#define FUSED_K_STEP(KC)                                                                   \
  {                                                                                        \
    constexpr int k = (KC);                                                                \
    const float* trp = trp2[k & 1];                                                        \
    /* A: T = K_k + W[k] -> Th/Tl */                                                       \
    _Pragma("unroll")                                                                      \
    for (int rf = 0; rf < 2; ++rf) {                                                       \
      int n0 = wave * 32 + rf * 16 + kgrp * 4;                                             \
      float nx0[4], nx1[4], na[4], nb[4], nc[4], nc1[4];                                   \
      _Pragma("unroll")                                                                    \
      for (int r = 0; r < 4; ++r) {                                                        \
        int n = n0 + r;                                                                    \
        nx0[r] = trp[n * 6 + 0]; nx1[r] = trp[n * 6 + 1]; na[r] = trp[n * 6 + 2];          \
        nb[r] = trp[n * 6 + 3]; nc[r] = trp[n * 6 + 4]; nc1[r] = trp[n * 6 + 5];           \
      }                                                                                    \
      _Pragma("unroll")                                                                    \
      for (int cf = 0; cf < 2; ++cf) {                                                     \
        int m = cf * 16 + lrow;                                                            \
        float mx0 = tp[m * 6 + 0], mx1 = tp[m * 6 + 1], ma = tp[m * 6 + 2];                \
        float mb = tp[m * 6 + 3], mc = tp[m * 6 + 4], mq = tp[m * 6 + 5];                  \
        float Tv[4];                                                                       \
        _Pragma("unroll")                                                                  \
        for (int r = 0; r < 4; ++r) {                                                      \
          float s00 = na[r] + ma, s11 = nb[r] + mb, s01 = nc[r] + mc;                      \
          float sdet = s00 * s11 - s01 * s01;                                              \
          float rsq = rsqrtf(fmaxf(sdet, 1e-5f));                                          \
          float d0 = nx0[r] - mx0, d1 = nx1[r] - mx1;                                      \
          float quad = s11 * d0 * d0 - 2.0f * s01 * d0 * d1 + s00 * d1 * d1;               \
          float u = 1.5f * quad * rsq * rsq;                                               \
          float tt = sqrtf(fmaxf(u, 3e-5f));                                               \
          float Kv = (1.0f + tt) * __expf(-tt) * nc1[r] * (mq * rsq);                      \
          Tv[r] = Kv + W[k][rf][cf][r];                                                    \
        }                                                                                  \
        unsigned hw[2], lw[2];                                                             \
        pack2(Tv[0], Tv[1], hw[0], lw[0]);                                                 \
        pack2(Tv[2], Tv[3], hw[1], lw[1]);                                                 \
        int off = m * 136 + n0;                                                            \
        *(uint2*)&Th[off] = make_uint2(hw[0], hw[1]);                                      \
        *(uint2*)&Tl[off] = make_uint2(lw[0], lw[1]);                                      \
      }                                                                                    \
    }                                                                                      \
    __syncthreads(); /* B */                                                               \
    /* C: wk = D_k * T (MFMA) + prefetch train rows for k+1 */                             \
    if (k < 7 && t < 128) {                                                                \
      size_t n = (size_t)b * kN + (k + 1) * 128 + t;                                       \
      float x0 = xt[n * 2 + 0];                                                            \
      float x1 = xt[n * 2 + 1];                                                            \
      float a = pt[n * 3 + 0];                                                             \
      float bb = pt[n * 3 + 1];                                                            \
      float c = pt[n * 3 + 2];                                                             \
      float det1 = a * bb - c * c;                                                         \
      trp2[(k + 1) & 1][t * 6 + 0] = x0; trp2[(k + 1) & 1][t * 6 + 1] = x1;                \
      trp2[(k + 1) & 1][t * 6 + 2] = a;  trp2[(k + 1) & 1][t * 6 + 3] = bb;                \
      trp2[(k + 1) & 1][t * 6 + 4] = c;                                                    \
      trp2[(k + 1) & 1][t * 6 + 5] = 2.0f * scale * sqrtf(sqrtf(det1));                    \
      zs2[(k + 1) & 1][t] = zbuf[n];                                                       \
    }                                                                                      \
    floatx4 wk[2][2];                                                                      \
    _Pragma("unroll")                                                                      \
    for (int rf = 0; rf < 2; ++rf)                                                         \
      _Pragma("unroll")                                                                    \
      for (int cf = 0; cf < 2; ++cf) wk[rf][cf] = (floatx4){0.f, 0.f, 0.f, 0.f};           \
    {                                                                                      \
      const unsigned short* Dhb = Dh + (size_t)(b * 8 + k) * 16384;                        \
      const unsigned short* Dlb = Dl + (size_t)(b * 8 + k) * 16384;                        \
      _Pragma("unroll")                                                                    \
      for (int ks = 0; ks < 4; ++ks) {                                                     \
        short8v bh[2], bl[2];                                                              \
        _Pragma("unroll")                                                                  \
        for (int cf = 0; cf < 2; ++cf) {                                                   \
          int boff = (cf * 16 + lrow) * 136 + ks * 32 + kgrp * 8;                          \
          bh[cf] = *(const short8v*)&Th[boff];                                             \
          bl[cf] = *(const short8v*)&Tl[boff];                                             \
        }                                                                                  \
        short8v ah[2], al[2];                                                              \
        _Pragma("unroll")                                                                  \
        for (int rf = 0; rf < 2; ++rf) {                                                   \
          size_t aoff = (size_t)(wave * 32 + rf * 16 + lrow) * 128 + ks * 32 + kgrp * 8;   \
          ah[rf] = *(const short8v*)&Dhb[aoff];                                            \
          al[rf] = *(const short8v*)&Dlb[aoff];                                            \
        }                                                                                  \
        _Pragma("unroll")                                                                  \
        for (int rf = 0; rf < 2; ++rf)                                                     \
          _Pragma("unroll")                                                                \
          for (int cf = 0; cf < 2; ++cf) {                                                 \
            wk[rf][cf] = __builtin_amdgcn_mfma_f32_16x16x32_bf16(ah[rf], bh[cf], wk[rf][cf], 0, 0, 0); \
            wk[rf][cf] = __builtin_amdgcn_mfma_f32_16x16x32_bf16(ah[rf], bl[cf], wk[rf][cf], 0, 0, 0); \
            wk[rf][cf] = __builtin_amdgcn_mfma_f32_16x16x32_bf16(al[rf], bh[cf], wk[rf][cf], 0, 0, 0); \
          }                                                                                \
      }                                                                                    \
    }                                                                                      \
    __syncthreads(); /* D */                                                               \
    /* E: store wk -> Th/Tl, accumulate pm/s2 */                                           \
    _Pragma("unroll")                                                                      \
    for (int rf = 0; rf < 2; ++rf) {                                                       \
      int n0 = wave * 32 + rf * 16 + kgrp * 4;                                             \
      _Pragma("unroll")                                                                    \
      for (int cf = 0; cf < 2; ++cf) {                                                     \
        int m = cf * 16 + lrow;                                                            \
        float wv[4];                                                                       \
        _Pragma("unroll")                                                                  \
        for (int r = 0; r < 4; ++r) {                                                      \
          wv[r] = wk[rf][cf][r];                                                           \
          pma[cf] = fmaf(wv[r], zs2[k & 1][n0 + r], pma[cf]);                              \
          s2a[cf] = fmaf(wv[r], wv[r], s2a[cf]);                                           \
        }                                                                                  \
        unsigned hw[2], lw[2];                                                             \
        pack2(wv[0], wv[1], hw[0], lw[0]);                                                 \
        pack2(wv[2], wv[3], hw[1], lw[1]);                                                 \
        int off = m * 136 + n0;                                                            \
        *(uint2*)&Th[off] = make_uint2(hw[0], hw[1]);                                      \
        *(uint2*)&Tl[off] = make_uint2(lw[0], lw[1]);                                      \
      }                                                                                    \
    }                                                                                      \
    __syncthreads(); /* F */                                                               \
    /* G: W[i] += (-Lh_ik) * w_k */                                                        \
    __builtin_amdgcn_s_setprio(1);                                                         \
    _Pragma("unroll")                                                                      \
    for (int ks = 0; ks < 4; ++ks) {                                                       \
      short8v bh[2], bl[2];                                                                \
      _Pragma("unroll")                                                                    \
      for (int cf = 0; cf < 2; ++cf) {                                                     \
        int boff = (cf * 16 + lrow) * 136 + ks * 32 + kgrp * 8;                            \
        bh[cf] = *(const short8v*)&Th[boff];                                               \
        bl[cf] = *(const short8v*)&Tl[boff];                                               \
      }                                                                                    \
      _Pragma("unroll")                                                                    \
      for (int i = k + 1; i < 8; ++i) {                                                    \
        short8v ah[2];                                                                     \
        _Pragma("unroll")                                                                  \
        for (int rf = 0; rf < 2; ++rf) {                                                   \
          size_t ro = (size_t)b * kN + i * 128 + wave * 32 + rf * 16 + lrow;               \
          size_t aoff = ro * kN + k * 128 + ks * 32 + kgrp * 8;                            \
          ah[rf] = *(const short8v*)&Lh[aoff];                                             \
        }                                                                                  \
        _Pragma("unroll")                                                                  \
        for (int rf = 0; rf < 2; ++rf)                                                     \
          _Pragma("unroll")                                                                \
          for (int cf = 0; cf < 2; ++cf) {                                                 \
            W[i][rf][cf] = __builtin_amdgcn_mfma_f32_16x16x32_bf16(ah[rf], bh[cf], W[i][rf][cf], 0, 0, 0); \
            W[i][rf][cf] = __builtin_amdgcn_mfma_f32_16x16x32_bf16(ah[rf], bl[cf], W[i][rf][cf], 0, 0, 0); \
          }                                                                                \
      }                                                                                    \
    }                                                                                      \
    __builtin_amdgcn_s_setprio(0);                                                         \
    __syncthreads(); /* H: Th/Tl free + prefetched trp visible for next step */            \
  }

  FUSED_K_STEP(0)
  FUSED_K_STEP(1)
  FUSED_K_STEP(2)
  FUSED_K_STEP(3)
  FUSED_K_STEP(4)
  FUSED_K_STEP(5)
  FUSED_K_STEP(6)
  FUSED_K_STEP(7)
#undef FUSED_K_STEP

#pragma unroll
  for (int cf = 0; cf < 2; ++cf) {
    int m = cf * 16 + lrow;
    red[m * 16 + wave * 4 + kgrp] = pma[cf];
    red[512 + m * 16 + wave * 4 + kgrp] = s2a[cf];
  }
  __syncthreads();
  if (t < 32) {
    float pm = 0.f, s2 = 0.f;
#pragma unroll
    for (int j = 0; j < 16; ++j) {
      pm += red[t * 16 + j];
      s2 += red[512 + t * 16 + j];
    }
    int mg = mt * 32 + t;
    float a = tp[t * 6 + 2], bb = tp[t * 6 + 3], c = tp[t * 6 + 4];
    float det = a * bb - c * c;
    float C = 2.0f * sqrtf(det) * rsqrtf(fmaxf(4.0f * det, 1e-5f));
    float t0 = kSqrt3 * sqrtf(1e-5f);
    float mat = (1.0f + t0) * __expf(-t0);
    float kd = C * mat * scale;
    out[b * kM + mg] = meanp[b] + pm;
    out[kB * kM + b * kM + mg] = kd - s2;
  }
}

extern "C" void kernel_launch(void* const* d_in, const int* in_sizes, int n_in,
                              void* d_out, int out_size, void* d_ws, size_t ws_size,
                              hipStream_t stream) {
  const float* xt = (const float*)d_in[0];
  const float* pt = (const float*)d_in[1];
  const float* xs = (const float*)d_in[2];
  const float* ps = (const float*)d_in[3];
  const float* y = (const float*)d_in[4];
  const float* var = (const float*)d_in[5];
  const float* meanp = (const float*)d_in[6];
  const float* sp = (const float*)d_in[7];
  float* out = (float*)d_out;
  char* ws = (char*)d_ws;
  if (ws_size < WS_BYTES) return;

  float* A = (float*)(ws + A_OFF);
  float* Dg = (float*)(ws + DG_OFF);
  float* zbuf = (float*)(ws + Z_OFF);
  unsigned short* Lh = (unsigned short*)(ws + LH_OFF);
  unsigned short* Dh = (unsigned short*)(ws + DH_OFF);
  unsigned short* Dl = (unsigned short*)(ws + DL_OFF);

  build_A<<<(kB * kN * kN) / 256, 256, 0, stream>>>(xt, pt, var, sp, A);
  for (int p = 0; p < 8; ++p) {
    chol_panel<<<kB, 1024, 0, stream>>>(A, Dg, Dh, Dl, p);
    if (p < 7) {
      int nt = 7 - p;
      chol_trsm<<<dim3(nt, kB), 256, 0, stream>>>(A, Dg, Lh, p);
      chol_syrk<<<dim3(nt * (nt + 1) / 2, kB), 256, 0, stream>>>(A, p);
    }
  }
  solve_small<<<kB, 1024, 0, stream>>>(A, Dg, y, meanp, zbuf, out);
  fused_mfma<<<kB * 512, 256, 0, stream>>>(Lh, Dh, Dl, xt, pt, xs, ps,
                                           sp, meanp, zbuf, out);
}